// Round 1
// baseline (591.494 us; speedup 1.0000x reference)
//
#include <hip/hip_runtime.h>
#include <math.h>

// SparseLinearAttention — fp32 baseline, MI355X (gfx950)
// B=2 H=16 L=2048 D=128, 64-row blocks, top-4 of 32 k-blocks per q-block.
static constexpr int BH   = 32;    // B*H
static constexpr int L    = 2048;
static constexpr int D    = 128;
static constexpr int NB   = 32;    // L/64 blocks
static constexpr int TOPK = 4;

// workspace layout (float slots)
static constexpr size_t QB_OFF  = 0;              // 32*32*128
static constexpr size_t KB_OFF  = 131072;
static constexpr size_t LUT_OFF = 262144;         // int[32*32*4]
static constexpr size_t KV_OFF  = 266240;         // 32*128*128 (atomic-accumulated)
static constexpr size_t KS_OFF  = 790528;         // 32*128
static constexpr size_t A_OFF   = 794624;         // 32*128*128  A = kvsum @ w^T

// ---------------- K1: per-64-row block means of q and k ----------------
__global__ __launch_bounds__(128) void k_blockmean(
    const float* __restrict__ q, const float* __restrict__ k,
    float* __restrict__ qb, float* __restrict__ kb) {
  int bid = blockIdx.x;
  int bh = bid >> 5, blk = bid & 31;
  int d = threadIdx.x;
  const float* qp = q + ((size_t)(bh * L + blk * 64)) * D + d;
  const float* kp = k + ((size_t)(bh * L + blk * 64)) * D + d;
  float sq = 0.f, sk = 0.f;
#pragma unroll 8
  for (int r = 0; r < 64; ++r) { sq += qp[(size_t)r * D]; sk += kp[(size_t)r * D]; }
  qb[(bh * NB + blk) * D + d] = sq * (1.f / 64.f);
  kb[(bh * NB + blk) * D + d] = sk * (1.f / 64.f);
}

// ---------------- K2: 32x32 block scores + top-4 per row ----------------
__global__ __launch_bounds__(256) void k_scores_topk(
    const float* __restrict__ qb, const float* __restrict__ kb, int* __restrict__ lut) {
  __shared__ float qs[NB * D];       // plain
  __shared__ float ks[NB * 132];     // +4 pad: kc-varying reads spread banks
  __shared__ float sc[NB * 33];
  int bh = blockIdx.x, t = threadIdx.x;
  const float4* qg = (const float4*)(qb + (size_t)bh * NB * D);
  const float4* kg = (const float4*)(kb + (size_t)bh * NB * D);
  float4* qs4 = (float4*)qs;
  float4* ks4 = (float4*)ks;
#pragma unroll
  for (int it = 0; it < 4; ++it) {
    int p = t + 256 * it;            // 1024 float4 total
    int row = p >> 5, c = p & 31;
    qs4[p] = qg[p];
    ks4[row * 33 + c] = kg[p];
  }
  __syncthreads();
#pragma unroll
  for (int ss = 0; ss < 4; ++ss) {
    int idx = t + 256 * ss;
    int qr = idx >> 5, kc = idx & 31;
    float acc = 0.f;
#pragma unroll
    for (int c = 0; c < 32; ++c) {
      float4 a = qs4[qr * 32 + c];
      float4 b = ks4[kc * 33 + c];
      acc += a.x * b.x + a.y * b.y + a.z * b.z + a.w * b.w;
    }
    sc[qr * 33 + kc] = acc;
  }
  __syncthreads();
  if (t < NB) {                       // top-4 by repeated masked max (set == lax.top_k set)
    unsigned mask = 0;
    for (int s = 0; s < TOPK; ++s) {
      float best = -INFINITY; int bi = 0;
      for (int j = 0; j < NB; ++j) {
        float vv = sc[t * 33 + j];
        if (!((mask >> j) & 1u) && vv > best) { best = vv; bi = j; }
      }
      mask |= 1u << bi;
      lut[((size_t)(bh * NB) + t) * TOPK + s] = bi;
    }
  }
}

// ---------------- K3: flash-style sparse attention over 4 gathered blocks ----
// thread (i,g): i=t>>2 row 0..63, g=t&3. Owns S cols j=4*jj+g and O cols
// chunks c=g+4*ee. Q/K/V LDS tiles XOR-swizzled (c ^= row&7, float4 units):
//   Q read: 2-way (free); K read (4 distinct g rows): conflict-free;
//   V read: conflict-free. P buffer col = j ^ i: conflict-free reads.
__global__ __launch_bounds__(256) void k_sparse_attn(
    const float* __restrict__ q, const float* __restrict__ k, const float* __restrict__ v,
    const int* __restrict__ lut, float* __restrict__ out) {
  extern __shared__ float sm[];
  float* Qs  = sm;               // 8192 f
  float* KVs = sm + 8192;        // 8192 f (K then reused for V)
  float* Ps  = sm + 16384;       // 4096 f
  int qblk = blockIdx.x, bh = blockIdx.y;
  int t = threadIdx.x;
  int i = t >> 2, g = t & 3;
  float4* Qs4 = (float4*)Qs;
  float4* KVs4 = (float4*)KVs;
  const float4* qg = (const float4*)(q + ((size_t)(bh * L + qblk * 64)) * D);
#pragma unroll
  for (int it = 0; it < 8; ++it) {
    int p = t + 256 * it; int row = p >> 5, c = p & 31;
    Qs4[row * 32 + (c ^ (row & 7))] = qg[p];
  }
  float o[32];
#pragma unroll
  for (int e = 0; e < 32; ++e) o[e] = 0.f;
  float mrun = -INFINITY, lrun = 0.f;
  const float scale = 0.088388347648318447f;   // 1/sqrt(128)
  const int* lp = lut + ((size_t)(bh * NB) + qblk) * TOPK;
  for (int itb = 0; itb < TOPK; ++itb) {
    int kblk = lp[itb];
    const float4* kg = (const float4*)(k + ((size_t)(bh * L + kblk * 64)) * D);
    const float4* vg = (const float4*)(v + ((size_t)(bh * L + kblk * 64)) * D);
    __syncthreads();                 // prev PV done with KVs
#pragma unroll
    for (int it = 0; it < 8; ++it) {
      int p = t + 256 * it; int row = p >> 5, c = p & 31;
      KVs4[row * 32 + (c ^ (row & 7))] = kg[p];
    }
    __syncthreads();
    float s[16];
#pragma unroll
    for (int jj = 0; jj < 16; ++jj) s[jj] = 0.f;
    for (int c = 0; c < 32; ++c) {
      float4 qv = Qs4[i * 32 + (c ^ (i & 7))];
#pragma unroll
      for (int jj = 0; jj < 16; ++jj) {
        int j = (jj << 2) | g;
        float4 kv = KVs4[j * 32 + (c ^ (j & 7))];
        s[jj] += qv.x * kv.x + qv.y * kv.y + qv.z * kv.z + qv.w * kv.w;
      }
    }
    float mloc = -INFINITY;
#pragma unroll
    for (int jj = 0; jj < 16; ++jj) { s[jj] *= scale; mloc = fmaxf(mloc, s[jj]); }
    mloc = fmaxf(mloc, __shfl_xor(mloc, 1));
    mloc = fmaxf(mloc, __shfl_xor(mloc, 2));
    float mnew = fmaxf(mrun, mloc);
    float alpha = __expf(mrun - mnew);           // first iter: exp(-inf)=0
    float lloc = 0.f;
#pragma unroll
    for (int jj = 0; jj < 16; ++jj) {
      float pv = __expf(s[jj] - mnew);
      Ps[i * 64 + (((jj << 2) | g) ^ i)] = pv;
      lloc += pv;
    }
    lloc += __shfl_xor(lloc, 1);
    lloc += __shfl_xor(lloc, 2);
    lrun = lrun * alpha + lloc;
    mrun = mnew;
#pragma unroll
    for (int e = 0; e < 32; ++e) o[e] *= alpha;
    __syncthreads();                 // Ps visible; K reads done
#pragma unroll
    for (int it = 0; it < 8; ++it) {
      int p = t + 256 * it; int row = p >> 5, c = p & 31;
      KVs4[row * 32 + (c ^ (row & 7))] = vg[p];
    }
    __syncthreads();
    for (int j = 0; j < 64; ++j) {
      float pij = Ps[i * 64 + (j ^ i)];
#pragma unroll
      for (int ee = 0; ee < 8; ++ee) {
        int cc = g + (ee << 2);
        float4 vv = KVs4[j * 32 + (cc ^ (j & 7))];
        o[ee * 4 + 0] += pij * vv.x;
        o[ee * 4 + 1] += pij * vv.y;
        o[ee * 4 + 2] += pij * vv.z;
        o[ee * 4 + 3] += pij * vv.w;
      }
    }
  }
  float rinv = 1.f / lrun;
  float4* og = (float4*)(out + ((size_t)(bh * L + qblk * 64)) * D);
#pragma unroll
  for (int ee = 0; ee < 8; ++ee) {
    int cc = g + (ee << 2);
    float4 r;
    r.x = o[ee * 4 + 0] * rinv;
    r.y = o[ee * 4 + 1] * rinv;
    r.z = o[ee * 4 + 2] * rinv;
    r.w = o[ee * 4 + 3] * rinv;
    og[i * 32 + cc] = r;
  }
}

// ---------------- K4: phi_k = softmax(k,-1); kvsum += phi_k^T v; ksum += sum(phi_k)
// 8 slices of 256 rows per (b,h); outer product register-tiled: thread owns
// d = dg+8*dd (16), e = eg*4..+4 → 64 acc regs; fp32 atomics into ws.
__global__ __launch_bounds__(256) void k_kvsum(
    const float* __restrict__ k, const float* __restrict__ v,
    float* __restrict__ kvsum, float* __restrict__ ksum) {
  __shared__ float phis[32 * D];
  __shared__ float vs[32 * D];
  int bh = blockIdx.x >> 3, slice = blockIdx.x & 7;
  int t = threadIdx.x;
  int r = t >> 3, sub = t & 7;      // phase A roles (8 threads/row)
  int dg = t >> 5, eg = t & 31;     // phase B roles
  float acc[64];
#pragma unroll
  for (int u = 0; u < 64; ++u) acc[u] = 0.f;
  float kacc[16];
#pragma unroll
  for (int u = 0; u < 16; ++u) kacc[u] = 0.f;
  int base = slice * 256;
  for (int ch = 0; ch < 8; ++ch) {
    int row = base + ch * 32 + r;
    const float4* kr = (const float4*)(k + ((size_t)(bh * L + row)) * D) + sub * 4;
    const float4* vr = (const float4*)(v + ((size_t)(bh * L + row)) * D) + sub * 4;
    float x[16];
    {
      float4 a0 = kr[0], a1 = kr[1], a2 = kr[2], a3 = kr[3];
      x[0]=a0.x; x[1]=a0.y; x[2]=a0.z; x[3]=a0.w;
      x[4]=a1.x; x[5]=a1.y; x[6]=a1.z; x[7]=a1.w;
      x[8]=a2.x; x[9]=a2.y; x[10]=a2.z; x[11]=a2.w;
      x[12]=a3.x; x[13]=a3.y; x[14]=a3.z; x[15]=a3.w;
    }
    float mx = -INFINITY;
#pragma unroll
    for (int u = 0; u < 16; ++u) mx = fmaxf(mx, x[u]);
    mx = fmaxf(mx, __shfl_xor(mx, 1));
    mx = fmaxf(mx, __shfl_xor(mx, 2));
    mx = fmaxf(mx, __shfl_xor(mx, 4));
    float es = 0.f;
#pragma unroll
    for (int u = 0; u < 16; ++u) { x[u] = __expf(x[u] - mx); es += x[u]; }
    es += __shfl_xor(es, 1);
    es += __shfl_xor(es, 2);
    es += __shfl_xor(es, 4);
    float inv = 1.f / es;
    float4 v0 = vr[0], v1 = vr[1], v2 = vr[2], v3 = vr[3];
    __syncthreads();                 // prev chunk's phase B done
#pragma unroll
    for (int u = 0; u < 16; ++u) {
      float ph = x[u] * inv;
      phis[r * D + sub * 16 + u] = ph;
      kacc[u] += ph;
    }
    {
      float4* vdst = (float4*)(vs + r * D + sub * 16);
      vdst[0] = v0; vdst[1] = v1; vdst[2] = v2; vdst[3] = v3;
    }
    __syncthreads();
    const float4* vs4 = (const float4*)vs;
    for (int rr = 0; rr < 32; ++rr) {
      float4 vv = vs4[rr * 32 + eg];
#pragma unroll
      for (int dd = 0; dd < 16; ++dd) {
        float ph = phis[rr * D + dg + (dd << 3)];
        acc[dd * 4 + 0] += ph * vv.x;
        acc[dd * 4 + 1] += ph * vv.y;
        acc[dd * 4 + 2] += ph * vv.z;
        acc[dd * 4 + 3] += ph * vv.w;
      }
    }
  }
#pragma unroll
  for (int dd = 0; dd < 16; ++dd) {
    int d = dg + (dd << 3);
    float* dst = kvsum + ((size_t)(bh * D + d)) * D + eg * 4;
    atomicAdd(dst + 0, acc[dd * 4 + 0]);
    atomicAdd(dst + 1, acc[dd * 4 + 1]);
    atomicAdd(dst + 2, acc[dd * 4 + 2]);
    atomicAdd(dst + 3, acc[dd * 4 + 3]);
  }
  __syncthreads();
#pragma unroll
  for (int u = 0; u < 16; ++u) phis[r * D + sub * 16 + u] = kacc[u];
  __syncthreads();
  if (t < D) {
    float ssum = 0.f;
#pragma unroll
    for (int rr = 0; rr < 32; ++rr) ssum += phis[rr * D + t];
    atomicAdd(&ksum[bh * D + t], ssum);
  }
}

// ---------------- K5: A[d][j] = sum_e kvsum[d][e] * w[j][e] ----------------
__global__ __launch_bounds__(256) void k_projA(
    const float* __restrict__ kvsum, const float* __restrict__ w, float* __restrict__ A) {
  __shared__ float wts[D * D];       // swizzled: wts[e*128 + ((j+e)&127)] = w[j][e]
  int dquad = blockIdx.x, bh = blockIdx.y;
  int t = threadIdx.x;
  const float4* wg = (const float4*)w;
#pragma unroll
  for (int it = 0; it < 16; ++it) {
    int p4 = t + 256 * it;
    int j = p4 >> 5, ebase = (p4 & 31) << 2;
    float4 val = wg[p4];
    wts[(ebase + 0) * D + ((j + ebase + 0) & 127)] = val.x;
    wts[(ebase + 1) * D + ((j + ebase + 1) & 127)] = val.y;
    wts[(ebase + 2) * D + ((j + ebase + 2) & 127)] = val.z;
    wts[(ebase + 3) * D + ((j + ebase + 3) & 127)] = val.w;
  }
  __syncthreads();
  int j = t & 127, dh = t >> 7;
  int dbase = dquad * 32 + dh * 16;
  const float* kvb = kvsum + ((size_t)(bh * D + dbase)) * D;  // uniform → L1-broadcast
  float acc[16];
#pragma unroll
  for (int u = 0; u < 16; ++u) acc[u] = 0.f;
  for (int e = 0; e < D; ++e) {
    float wv = wts[e * D + ((j + e) & 127)];
#pragma unroll
    for (int dd = 0; dd < 16; ++dd)
      acc[dd] += kvb[dd * D + e] * wv;
  }
#pragma unroll
  for (int dd = 0; dd < 16; ++dd)
    A[((size_t)(bh * D + dbase + dd)) * D + j] = acc[dd];
}

// ---------------- K6: out += (softmax(q) @ A)/den + b_proj ----------------
__global__ __launch_bounds__(256) void k_linear_out(
    const float* __restrict__ q, const float* __restrict__ A,
    const float* __restrict__ ksum, const float* __restrict__ bproj,
    float* __restrict__ out) {
  extern __shared__ float sm[];
  float* As    = sm;                     // 16384 f
  float* phis  = sm + 16384;             // 32*132 padded
  float* ksums = sm + 16384 + 32 * 132;  // 128 f
  int rb = blockIdx.x, bh = blockIdx.y;
  int t = threadIdx.x;
  int r = t >> 3, sub = t & 7;
  const float4* Ag = (const float4*)(A + (size_t)bh * D * D);
  float4* As4 = (float4*)As;
#pragma unroll
  for (int it = 0; it < 16; ++it) {
    int p = t + 256 * it;
    As4[p] = Ag[p];
  }
  if (t < D) ksums[t] = ksum[bh * D + t];
  int row = rb * 32 + r;
  const float4* qr4 = (const float4*)(q + ((size_t)(bh * L + row)) * D) + sub * 4;
  float x[16];
  {
    float4 a0 = qr4[0], a1 = qr4[1], a2 = qr4[2], a3 = qr4[3];
    x[0]=a0.x; x[1]=a0.y; x[2]=a0.z; x[3]=a0.w;
    x[4]=a1.x; x[5]=a1.y; x[6]=a1.z; x[7]=a1.w;
    x[8]=a2.x; x[9]=a2.y; x[10]=a2.z; x[11]=a2.w;
    x[12]=a3.x; x[13]=a3.y; x[14]=a3.z; x[15]=a3.w;
  }
  float mx = -INFINITY;
#pragma unroll
  for (int u = 0; u < 16; ++u) mx = fmaxf(mx, x[u]);
  mx = fmaxf(mx, __shfl_xor(mx, 1));
  mx = fmaxf(mx, __shfl_xor(mx, 2));
  mx = fmaxf(mx, __shfl_xor(mx, 4));
  float es = 0.f;
#pragma unroll
  for (int u = 0; u < 16; ++u) { x[u] = __expf(x[u] - mx); es += x[u]; }
  es += __shfl_xor(es, 1);
  es += __shfl_xor(es, 2);
  es += __shfl_xor(es, 4);
  float inv = 1.f / es;
  __syncthreads();                      // As + ksums resident
  float dloc = 0.f;
#pragma unroll
  for (int u = 0; u < 16; ++u) {
    float ph = x[u] * inv;
    phis[r * 132 + sub * 16 + u] = ph;
    dloc += ph * ksums[sub * 16 + u];
  }
  dloc += __shfl_xor(dloc, 1);
  dloc += __shfl_xor(dloc, 2);
  dloc += __shfl_xor(dloc, 4);
  float rden = 1.f / (1e-5f + dloc);
  __syncthreads();                      // phis complete
  float4 acc[4];
#pragma unroll
  for (int ee = 0; ee < 4; ++ee) { acc[ee].x = 0.f; acc[ee].y = 0.f; acc[ee].z = 0.f; acc[ee].w = 0.f; }
  for (int f = 0; f < D; ++f) {
    float ph = phis[r * 132 + f];
#pragma unroll
    for (int ee = 0; ee < 4; ++ee) {
      float4 av = As4[f * 32 + sub + (ee << 3)];
      acc[ee].x += ph * av.x;
      acc[ee].y += ph * av.y;
      acc[ee].z += ph * av.z;
      acc[ee].w += ph * av.w;
    }
  }
  float4* og = (float4*)(out + ((size_t)(bh * L + row)) * D);
  const float4* bg = (const float4*)bproj;
#pragma unroll
  for (int ee = 0; ee < 4; ++ee) {
    int c = sub + (ee << 3);
    float4 oo = og[c];
    float4 bb = bg[c];
    oo.x += acc[ee].x * rden + bb.x;
    oo.y += acc[ee].y * rden + bb.y;
    oo.z += acc[ee].z * rden + bb.z;
    oo.w += acc[ee].w * rden + bb.w;
    og[c] = oo;
  }
}

extern "C" void kernel_launch(void* const* d_in, const int* in_sizes, int n_in,
                              void* d_out, int out_size, void* d_ws, size_t ws_size,
                              hipStream_t stream) {
  const float* q = (const float*)d_in[0];
  const float* k = (const float*)d_in[1];
  const float* v = (const float*)d_in[2];
  const float* w = (const float*)d_in[3];
  const float* b = (const float*)d_in[4];
  float* out = (float*)d_out;
  float* ws = (float*)d_ws;
  float* qb    = ws + QB_OFF;
  float* kb    = ws + KB_OFF;
  int*   lut   = (int*)(ws + LUT_OFF);
  float* kvsum = ws + KV_OFF;
  float* ksum  = ws + KS_OFF;
  float* A     = ws + A_OFF;

  // raise dynamic-LDS cap (81920 B / 82944 B); idempotent, capture-safe
  hipFuncSetAttribute(reinterpret_cast<const void*>(k_sparse_attn),
                      hipFuncAttributeMaxDynamicSharedMemorySize, 81920);
  hipFuncSetAttribute(reinterpret_cast<const void*>(k_linear_out),
                      hipFuncAttributeMaxDynamicSharedMemorySize, 82944);

  // zero the atomic accumulators (kvsum + ksum are contiguous)
  hipMemsetAsync(kvsum, 0, (size_t)(524288 + 4096) * sizeof(float), stream);

  k_blockmean  <<<dim3(BH * NB), dim3(128), 0, stream>>>(q, k, qb, kb);
  k_scores_topk<<<dim3(BH),      dim3(256), 0, stream>>>(qb, kb, lut);
  k_sparse_attn<<<dim3(NB, BH),  dim3(256), 81920, stream>>>(q, k, v, lut, out);
  k_kvsum      <<<dim3(BH * 8),  dim3(256), 0, stream>>>(k, v, kvsum, ksum);
  k_projA      <<<dim3(4, BH),   dim3(256), 0, stream>>>(kvsum, w, A);
  k_linear_out <<<dim3(64, BH),  dim3(256), 82944, stream>>>(q, A, ksum, b, out);
}

// Round 2
// 429.736 us; speedup vs baseline: 1.3764x; 1.3764x over previous
//
#include <hip/hip_runtime.h>
#include <math.h>

// SparseLinearAttention R2 — MFMA bf16x3 sparse attention, MI355X (gfx950)
// B=2 H=16 L=2048 D=128, 64-row blocks, top-4 of 32 k-blocks per q-block.
static constexpr int BH   = 32;
static constexpr int L    = 2048;
static constexpr int D    = 128;
static constexpr int NB   = 32;
static constexpr int TOPK = 4;

// workspace layout (float slots); total 18,096,128 floats = 72.4 MB
static constexpr size_t QB_OFF   = 0;         // 32*32*128
static constexpr size_t KB_OFF   = 131072;
static constexpr size_t LUT_OFF  = 262144;    // int[32*32*4]
static constexpr size_t KV_OFF   = 266240;    // 32*128*128 (atomic)
static constexpr size_t KS_OFF   = 790528;    // 32*128
static constexpr size_t A_OFF    = 794624;    // 32*128*128
static constexpr size_t KHI_OFF  = 1318912;   // bf16 2048*128*32 (as 4.19M floats)
static constexpr size_t KLO_OFF  = 5513216;
static constexpr size_t VTHI_OFF = 9707520;   // transposed per 64-blk: [bh][kblk][128][64]
static constexpr size_t VTLO_OFF = 13901824;

typedef __attribute__((ext_vector_type(8))) short short8;
typedef __attribute__((ext_vector_type(4))) float f32x4;

__device__ __forceinline__ unsigned short f2bf(float x) {   // RNE fp32->bf16
  unsigned u = __float_as_uint(x);
  u += 0x7fffu + ((u >> 16) & 1u);
  return (unsigned short)(u >> 16);
}
__device__ __forceinline__ float bf2f(unsigned short h) {
  return __uint_as_float(((unsigned)h) << 16);
}
__device__ __forceinline__ f32x4 mfma16(short8 a, short8 b, f32x4 c) {
  return __builtin_amdgcn_mfma_f32_16x16x32_bf16(a, b, c, 0, 0, 0);
}
__device__ __forceinline__ void gl_lds16(const void* g, void* l) {
  __builtin_amdgcn_global_load_lds(
      (const __attribute__((address_space(1))) unsigned int*)g,
      (__attribute__((address_space(3))) unsigned int*)l, 16, 0, 0);
}

// ---------------- K0: block means + bf16 hi/lo conversion + V transpose ------
__global__ __launch_bounds__(256) void k_prep(
    const float* __restrict__ q, const float* __restrict__ k, const float* __restrict__ v,
    float* __restrict__ qb, float* __restrict__ kb,
    unsigned short* __restrict__ khi, unsigned short* __restrict__ klo,
    unsigned short* __restrict__ vthi, unsigned short* __restrict__ vtlo) {
  __shared__ float Vs[64 * 128];     // swizzled fp32 v tile (quad ^= (row>>2)&7)
  __shared__ float part[8 * 128];
  int bid = blockIdx.x;
  int t = threadIdx.x;
  size_t rb = (size_t)bid * 64 * D;  // bid = bh*NB + kblk; rows contiguous
  int c = t & 31, g = t >> 5;
  // stage v swizzled
  const float4* v4 = (const float4*)(v + rb);
  float4* Vs4 = (float4*)Vs;
#pragma unroll
  for (int it = 0; it < 8; ++it) {
    int p = t + 256 * it;
    int row = p >> 5, cq = p & 31;
    Vs4[row * 32 + (cq ^ ((row >> 2) & 7))] = v4[p];
  }
  // q mean
  float4 qs = {0.f, 0.f, 0.f, 0.f};
#pragma unroll
  for (int it = 0; it < 8; ++it) {
    int row = g + 8 * it;
    float4 xv = *(const float4*)(q + rb + (size_t)row * D + 4 * c);
    qs.x += xv.x; qs.y += xv.y; qs.z += xv.z; qs.w += xv.w;
  }
  ((float4*)part)[g * 32 + c] = qs;
  __syncthreads();
  if (t < 128) {
    float s = 0.f;
#pragma unroll
    for (int gg = 0; gg < 8; ++gg) s += part[gg * 128 + t];
    qb[(size_t)bid * D + t] = s * (1.f / 64.f);
  }
  __syncthreads();
  // k: convert + mean
  float4 ks = {0.f, 0.f, 0.f, 0.f};
#pragma unroll
  for (int it = 0; it < 8; ++it) {
    int row = g + 8 * it;
    size_t off = rb + (size_t)row * D + 4 * c;
    float4 xv = *(const float4*)(k + off);
    ushort4 h, l;
    h.x = f2bf(xv.x); l.x = f2bf(xv.x - bf2f(h.x));
    h.y = f2bf(xv.y); l.y = f2bf(xv.y - bf2f(h.y));
    h.z = f2bf(xv.z); l.z = f2bf(xv.z - bf2f(h.z));
    h.w = f2bf(xv.w); l.w = f2bf(xv.w - bf2f(h.w));
    *(ushort4*)(khi + off) = h;
    *(ushort4*)(klo + off) = l;
    ks.x += xv.x; ks.y += xv.y; ks.z += xv.z; ks.w += xv.w;
  }
  ((float4*)part)[g * 32 + c] = ks;
  __syncthreads();
  if (t < 128) {
    float s = 0.f;
#pragma unroll
    for (int gg = 0; gg < 8; ++gg) s += part[gg * 128 + t];
    kb[(size_t)bid * D + t] = s * (1.f / 64.f);
  }
  __syncthreads();
  // emit vt hi/lo: [bid][d][j], rows of 64 bf16 (128B)
  size_t tb = (size_t)bid * 8192;
#pragma unroll
  for (int pp = 0; pp < 4; ++pp) {
    int d = 32 * pp + (t >> 3);
    int jc = t & 7;
    unsigned hs[8], ls[8];
#pragma unroll
    for (int i = 0; i < 8; ++i) {
      int j = jc * 8 + i;
      float x = Vs[j * 128 + (d ^ (j & 28))];
      unsigned short hh = f2bf(x);
      hs[i] = hh; ls[i] = f2bf(x - bf2f(hh));
    }
    int4 hw, lw;
    hw.x = (int)(hs[0] | (hs[1] << 16)); hw.y = (int)(hs[2] | (hs[3] << 16));
    hw.z = (int)(hs[4] | (hs[5] << 16)); hw.w = (int)(hs[6] | (hs[7] << 16));
    lw.x = (int)(ls[0] | (ls[1] << 16)); lw.y = (int)(ls[2] | (ls[3] << 16));
    lw.z = (int)(ls[4] | (ls[5] << 16)); lw.w = (int)(ls[6] | (ls[7] << 16));
    *(int4*)(vthi + tb + (size_t)d * 64 + jc * 8) = hw;
    *(int4*)(vtlo + tb + (size_t)d * 64 + jc * 8) = lw;
  }
}

// ---------------- K2: 32x32 block scores + top-4 per row ----------------
__global__ __launch_bounds__(256) void k_scores_topk(
    const float* __restrict__ qb, const float* __restrict__ kb, int* __restrict__ lut) {
  __shared__ float qs[NB * D];
  __shared__ float ks[NB * 132];
  __shared__ float sc[NB * 33];
  int bh = blockIdx.x, t = threadIdx.x;
  const float4* qg = (const float4*)(qb + (size_t)bh * NB * D);
  const float4* kg = (const float4*)(kb + (size_t)bh * NB * D);
  float4* qs4 = (float4*)qs;
  float4* ks4 = (float4*)ks;
#pragma unroll
  for (int it = 0; it < 4; ++it) {
    int p = t + 256 * it;
    int row = p >> 5, c = p & 31;
    qs4[p] = qg[p];
    ks4[row * 33 + c] = kg[p];
  }
  __syncthreads();
#pragma unroll
  for (int ss = 0; ss < 4; ++ss) {
    int idx = t + 256 * ss;
    int qr = idx >> 5, kc = idx & 31;
    float acc = 0.f;
#pragma unroll
    for (int c = 0; c < 32; ++c) {
      float4 a = qs4[qr * 32 + c];
      float4 b = ks4[kc * 33 + c];
      acc += a.x * b.x + a.y * b.y + a.z * b.z + a.w * b.w;
    }
    sc[qr * 33 + kc] = acc;
  }
  __syncthreads();
  if (t < NB) {    // lowest index wins ties, like lax.top_k
    unsigned mask = 0;
    for (int s = 0; s < TOPK; ++s) {
      float best = -INFINITY; int bi = 0;
      for (int j = 0; j < NB; ++j) {
        float vv = sc[t * 33 + j];
        if (!((mask >> j) & 1u) && vv > best) { best = vv; bi = j; }
      }
      mask |= 1u << bi;
      lut[((size_t)(bh * NB) + t) * TOPK + s] = bi;
    }
  }
}

// ---------------- K3: MFMA flash sparse attention -----------------------
// 4 waves; wave w owns q-rows 16w..16w+15. Swapped QK^T: sacc[tk][r] =
// S[q=lr][kcol=16tk+4lg+r]. K/Vt staged via global_load_lds, slot^(row&7)
// XOR swizzle (pre-swizzled global source, rule 21). Per-wave P buffer.
__global__ __launch_bounds__(256) void k_attn(
    const float* __restrict__ q,
    const unsigned short* __restrict__ khi, const unsigned short* __restrict__ klo,
    const unsigned short* __restrict__ vthi, const unsigned short* __restrict__ vtlo,
    const int* __restrict__ lut, float* __restrict__ out) {
  extern __shared__ char sm[];
  char* KsH = sm;                 // 16KB each
  char* KsL = sm + 16384;
  char* VsH = sm + 32768;
  char* VsL = sm + 49152;
  int qblk = blockIdx.x, bh = blockIdx.y;
  int t = threadIdx.x, lane = t & 63, w = t >> 6;
  char* PwH = sm + 65536 + w * 4096;   // per-wave P: 16x64 bf16 hi (2KB) + lo
  char* PwL = PwH + 2048;
  int lr = lane & 15, lg = lane >> 4;
  const float scale = 0.088388347648318447f;   // 1/sqrt(128)

  // Q fragments straight from global (each element read exactly once)
  short8 qh[4], ql[4];
  const float* qrow = q + ((size_t)bh * L + (size_t)qblk * 64 + 16 * w + lr) * D;
#pragma unroll
  for (int s = 0; s < 4; ++s) {
    float4 x0 = *(const float4*)(qrow + 32 * s + 8 * lg);
    float4 x1 = *(const float4*)(qrow + 32 * s + 8 * lg + 4);
    float xs[8] = {x0.x, x0.y, x0.z, x0.w, x1.x, x1.y, x1.z, x1.w};
    short8 hv, lv;
#pragma unroll
    for (int i = 0; i < 8; ++i) {
      unsigned short h = f2bf(xs[i]);
      hv[i] = (short)h;
      lv[i] = (short)f2bf(xs[i] - bf2f(h));
    }
    qh[s] = hv; ql[s] = lv;
  }

  f32x4 oacc[8];
#pragma unroll
  for (int i = 0; i < 8; ++i) oacc[i] = (f32x4){0.f, 0.f, 0.f, 0.f};
  float mrun = -INFINITY, lrun = 0.f;

  const int* lp = lut + ((size_t)bh * NB + qblk) * TOPK;
  for (int itb = 0; itb < TOPK; ++itb) {
    int kblk = lp[itb];
    __syncthreads();               // prev iter's LDS reads complete
    {
      const char* kbh = (const char*)(khi + ((size_t)bh * L + (size_t)kblk * 64) * D);
      const char* kbl = (const char*)(klo + ((size_t)bh * L + (size_t)kblk * 64) * D);
      const char* vbh = (const char*)(vthi + ((size_t)(bh * NB + kblk)) * 8192);
      const char* vbl = (const char*)(vtlo + ((size_t)(bh * NB + kblk)) * 8192);
#pragma unroll
      for (int jj = 0; jj < 4; ++jj) {
        int ib = 4 * w + jj;
        {  // K tiles: 256B rows, 4 rows / instr
          int lrow = 4 * ib + (lane >> 4);
          int soff = lrow * 256 + (((lane & 15) ^ (lrow & 7)) << 4);
          gl_lds16(kbh + soff, KsH + ib * 1024);
          gl_lds16(kbl + soff, KsL + ib * 1024);
        }
        {  // Vt tiles: 128B rows, 8 rows / instr
          int lrow = 8 * ib + (lane >> 3);
          int soff = lrow * 128 + (((lane & 7) ^ (lrow & 7)) << 4);
          gl_lds16(vbh + soff, VsH + ib * 1024);
          gl_lds16(vbl + soff, VsL + ib * 1024);
        }
      }
    }
    __syncthreads();               // includes vmcnt(0) drain
    // ---- QK^T
    f32x4 sacc[4];
#pragma unroll
    for (int i = 0; i < 4; ++i) sacc[i] = (f32x4){0.f, 0.f, 0.f, 0.f};
#pragma unroll
    for (int s = 0; s < 4; ++s) {
#pragma unroll
      for (int tk = 0; tk < 4; ++tk) {
        int krow = 16 * tk + lr;
        int off = krow * 256 + (((4 * s + lg) ^ (krow & 7)) << 4);
        short8 kH = *(const short8*)(KsH + off);
        short8 kL = *(const short8*)(KsL + off);
        sacc[tk] = mfma16(kH, qh[s], sacc[tk]);
        sacc[tk] = mfma16(kL, qh[s], sacc[tk]);
        sacc[tk] = mfma16(kH, ql[s], sacc[tk]);
      }
    }
    // ---- online softmax (lane owns q-row lr; 16 kcols = 16tk+4lg+r)
    float mloc = -INFINITY;
#pragma unroll
    for (int tk = 0; tk < 4; ++tk)
#pragma unroll
      for (int r = 0; r < 4; ++r) mloc = fmaxf(mloc, sacc[tk][r]);
    mloc = fmaxf(mloc, __shfl_xor(mloc, 16));
    mloc = fmaxf(mloc, __shfl_xor(mloc, 32));
    float mnew = fmaxf(mrun, mloc * scale);
    float alpha = __expf(mrun - mnew);
    float lloc = 0.f;
#pragma unroll
    for (int tk = 0; tk < 4; ++tk) {
      unsigned ph[4], pl[4];
#pragma unroll
      for (int r = 0; r < 4; ++r) {
        float pf = __expf(sacc[tk][r] * scale - mnew);
        lloc += pf;
        unsigned short hh = f2bf(pf);
        ph[r] = hh; pl[r] = f2bf(pf - bf2f(hh));
      }
      int j0b = 32 * tk + 8 * lg;                 // byte of j0 within P row
      int slot16 = j0b >> 4, half = (j0b >> 3) & 1;
      int off = lr * 128 + ((slot16 ^ (lr & 7)) << 4) + half * 8;
      *(int2*)(PwH + off) = make_int2((int)(ph[0] | (ph[1] << 16)),
                                      (int)(ph[2] | (ph[3] << 16)));
      *(int2*)(PwL + off) = make_int2((int)(pl[0] | (pl[1] << 16)),
                                      (int)(pl[2] | (pl[3] << 16)));
    }
    lloc += __shfl_xor(lloc, 16);
    lloc += __shfl_xor(lloc, 32);
    lrun = lrun * alpha + lloc;
    mrun = mnew;
    float ar[4];
#pragma unroll
    for (int r = 0; r < 4; ++r) ar[r] = __shfl(alpha, 4 * lg + r);
#pragma unroll
    for (int tv = 0; tv < 8; ++tv)
#pragma unroll
      for (int r = 0; r < 4; ++r) oacc[tv][r] *= ar[r];
    // ---- PV (P frag reads are wave-local; lgkmcnt ordering suffices)
#pragma unroll
    for (int ks = 0; ks < 2; ++ks) {
      int poff = lr * 128 + (((lg + 4 * ks) ^ (lr & 7)) << 4);
      short8 pH = *(const short8*)(PwH + poff);
      short8 pL = *(const short8*)(PwL + poff);
#pragma unroll
      for (int tv = 0; tv < 8; ++tv) {
        int vrow = 16 * tv + lr;
        int voff = vrow * 128 + (((lg + 4 * ks) ^ (vrow & 7)) << 4);
        short8 vH = *(const short8*)(VsH + voff);
        short8 vL = *(const short8*)(VsL + voff);
        oacc[tv] = mfma16(pH, vH, oacc[tv]);
        oacc[tv] = mfma16(pL, vH, oacc[tv]);
        oacc[tv] = mfma16(pH, vL, oacc[tv]);
      }
    }
  }
  // ---- epilogue
  float rinv[4];
#pragma unroll
  for (int r = 0; r < 4; ++r) rinv[r] = 1.f / __shfl(lrun, 4 * lg + r);
  float* ob = out + ((size_t)bh * L + (size_t)qblk * 64 + 16 * w) * D;
#pragma unroll
  for (int tv = 0; tv < 8; ++tv)
#pragma unroll
    for (int r = 0; r < 4; ++r)
      ob[(size_t)(4 * lg + r) * D + 16 * tv + lr] = oacc[tv][r] * rinv[r];
}

// ---------------- K4: phi_k softmax + kvsum/ksum (16 slices, f4 reads) ------
__global__ __launch_bounds__(256) void k_kvsum(
    const float* __restrict__ k, const float* __restrict__ v,
    float* __restrict__ kvsum, float* __restrict__ ksum) {
  __shared__ float phis[32 * D];
  __shared__ float vs[32 * D];
  int bh = blockIdx.x >> 4, slice = blockIdx.x & 15;
  int t = threadIdx.x;
  int r = t >> 3, sub = t & 7;
  int eg = t & 31, dg = t >> 5;
  f32x4 acc[4][4];
#pragma unroll
  for (int u = 0; u < 4; ++u)
#pragma unroll
    for (int dd = 0; dd < 4; ++dd) acc[u][dd] = (f32x4){0.f, 0.f, 0.f, 0.f};
  float kacc[16];
#pragma unroll
  for (int u = 0; u < 16; ++u) kacc[u] = 0.f;
  int base = slice * 128;
  for (int ch = 0; ch < 4; ++ch) {
    int row = base + ch * 32 + r;
    const float4* kr = (const float4*)(k + ((size_t)(bh * L + row)) * D) + sub * 4;
    const float4* vr = (const float4*)(v + ((size_t)(bh * L + row)) * D) + sub * 4;
    float x[16];
    {
      float4 a0 = kr[0], a1 = kr[1], a2 = kr[2], a3 = kr[3];
      x[0]=a0.x; x[1]=a0.y; x[2]=a0.z; x[3]=a0.w;
      x[4]=a1.x; x[5]=a1.y; x[6]=a1.z; x[7]=a1.w;
      x[8]=a2.x; x[9]=a2.y; x[10]=a2.z; x[11]=a2.w;
      x[12]=a3.x; x[13]=a3.y; x[14]=a3.z; x[15]=a3.w;
    }
    float mx = -INFINITY;
#pragma unroll
    for (int u = 0; u < 16; ++u) mx = fmaxf(mx, x[u]);
    mx = fmaxf(mx, __shfl_xor(mx, 1));
    mx = fmaxf(mx, __shfl_xor(mx, 2));
    mx = fmaxf(mx, __shfl_xor(mx, 4));
    float es = 0.f;
#pragma unroll
    for (int u = 0; u < 16; ++u) { x[u] = __expf(x[u] - mx); es += x[u]; }
    es += __shfl_xor(es, 1);
    es += __shfl_xor(es, 2);
    es += __shfl_xor(es, 4);
    float inv = 1.f / es;
    float4 v0 = vr[0], v1 = vr[1], v2 = vr[2], v3 = vr[3];
    __syncthreads();
#pragma unroll
    for (int u = 0; u < 16; ++u) {
      float ph = x[u] * inv;
      phis[r * D + sub * 16 + u] = ph;
      kacc[u] += ph;
    }
    {
      float4* vdst = (float4*)(vs + r * D + sub * 16);
      vdst[0] = v0; vdst[1] = v1; vdst[2] = v2; vdst[3] = v3;
    }
    __syncthreads();
    const f32x4* vs4 = (const f32x4*)vs;
    const f32x4* ph4p = (const f32x4*)phis;
    for (int rr = 0; rr < 32; ++rr) {
      f32x4 vv = vs4[rr * 32 + eg];
#pragma unroll
      for (int u = 0; u < 4; ++u) {
        f32x4 p4 = ph4p[rr * 32 + dg + 8 * u];
#pragma unroll
        for (int dd = 0; dd < 4; ++dd) acc[u][dd] += p4[dd] * vv;
      }
    }
  }
#pragma unroll
  for (int u = 0; u < 4; ++u)
#pragma unroll
    for (int dd = 0; dd < 4; ++dd) {
      int d = 4 * dg + 32 * u + dd;
      float* dst = kvsum + ((size_t)bh * D + d) * D + eg * 4;
      atomicAdd(dst + 0, acc[u][dd][0]);
      atomicAdd(dst + 1, acc[u][dd][1]);
      atomicAdd(dst + 2, acc[u][dd][2]);
      atomicAdd(dst + 3, acc[u][dd][3]);
    }
  __syncthreads();
#pragma unroll
  for (int u = 0; u < 16; ++u) phis[r * D + sub * 16 + u] = kacc[u];
  __syncthreads();
  if (t < D) {
    float s = 0.f;
#pragma unroll
    for (int rr = 0; rr < 32; ++rr) s += phis[rr * D + t];
    atomicAdd(&ksum[bh * D + t], s);
  }
}

// ---------------- K5: A[d][j] = sum_e kvsum[d][e] * w[j][e] ----------------
__global__ __launch_bounds__(256) void k_projA(
    const float* __restrict__ kvsum, const float* __restrict__ w, float* __restrict__ A) {
  __shared__ float wts[D * D];
  int dquad = blockIdx.x, bh = blockIdx.y;
  int t = threadIdx.x;
  const float4* wg = (const float4*)w;
#pragma unroll
  for (int it = 0; it < 16; ++it) {
    int p4 = t + 256 * it;
    int j = p4 >> 5, ebase = (p4 & 31) << 2;
    float4 val = wg[p4];
    wts[(ebase + 0) * D + ((j + ebase + 0) & 127)] = val.x;
    wts[(ebase + 1) * D + ((j + ebase + 1) & 127)] = val.y;
    wts[(ebase + 2) * D + ((j + ebase + 2) & 127)] = val.z;
    wts[(ebase + 3) * D + ((j + ebase + 3) & 127)] = val.w;
  }
  __syncthreads();
  int j = t & 127, dh = t >> 7;
  int dbase = dquad * 32 + dh * 16;
  const float* kvb = kvsum + ((size_t)(bh * D + dbase)) * D;
  float acc[16];
#pragma unroll
  for (int u = 0; u < 16; ++u) acc[u] = 0.f;
  for (int e = 0; e < D; ++e) {
    float wv = wts[e * D + ((j + e) & 127)];
#pragma unroll
    for (int dd = 0; dd < 16; ++dd)
      acc[dd] += kvb[dd * D + e] * wv;
  }
#pragma unroll
  for (int dd = 0; dd < 16; ++dd)
    A[((size_t)(bh * D + dbase + dd)) * D + j] = acc[dd];
}

// ---------------- K6: out += (softmax(q) @ A)/den + b_proj ----------------
__global__ __launch_bounds__(256) void k_linear_out(
    const float* __restrict__ q, const float* __restrict__ A,
    const float* __restrict__ ksum, const float* __restrict__ bproj,
    float* __restrict__ out) {
  extern __shared__ float smf[];
  float* As    = smf;
  float* phis  = smf + 16384;
  float* ksums = smf + 16384 + 32 * 132;
  int rb = blockIdx.x, bh = blockIdx.y;
  int t = threadIdx.x;
  int r = t >> 3, sub = t & 7;
  const float4* Ag = (const float4*)(A + (size_t)bh * D * D);
  float4* As4 = (float4*)As;
#pragma unroll
  for (int it = 0; it < 16; ++it) {
    int p = t + 256 * it;
    As4[p] = Ag[p];
  }
  if (t < D) ksums[t] = ksum[bh * D + t];
  int row = rb * 32 + r;
  const float4* qr4 = (const float4*)(q + ((size_t)(bh * L + row)) * D) + sub * 4;
  float x[16];
  {
    float4 a0 = qr4[0], a1 = qr4[1], a2 = qr4[2], a3 = qr4[3];
    x[0]=a0.x; x[1]=a0.y; x[2]=a0.z; x[3]=a0.w;
    x[4]=a1.x; x[5]=a1.y; x[6]=a1.z; x[7]=a1.w;
    x[8]=a2.x; x[9]=a2.y; x[10]=a2.z; x[11]=a2.w;
    x[12]=a3.x; x[13]=a3.y; x[14]=a3.z; x[15]=a3.w;
  }
  float mx = -INFINITY;
#pragma unroll
  for (int u = 0; u < 16; ++u) mx = fmaxf(mx, x[u]);
  mx = fmaxf(mx, __shfl_xor(mx, 1));
  mx = fmaxf(mx, __shfl_xor(mx, 2));
  mx = fmaxf(mx, __shfl_xor(mx, 4));
  float es = 0.f;
#pragma unroll
  for (int u = 0; u < 16; ++u) { x[u] = __expf(x[u] - mx); es += x[u]; }
  es += __shfl_xor(es, 1);
  es += __shfl_xor(es, 2);
  es += __shfl_xor(es, 4);
  float inv = 1.f / es;
  __syncthreads();
  float dloc = 0.f;
#pragma unroll
  for (int u = 0; u < 16; ++u) {
    float ph = x[u] * inv;
    phis[r * 132 + sub * 16 + u] = ph;
    dloc += ph * ksums[sub * 16 + u];
  }
  dloc += __shfl_xor(dloc, 1);
  dloc += __shfl_xor(dloc, 2);
  dloc += __shfl_xor(dloc, 4);
  float rden = 1.f / (1e-5f + dloc);
  __syncthreads();
  float4 acc[4];
#pragma unroll
  for (int ee = 0; ee < 4; ++ee) { acc[ee].x = 0.f; acc[ee].y = 0.f; acc[ee].z = 0.f; acc[ee].w = 0.f; }
  for (int f = 0; f < D; ++f) {
    float ph = phis[r * 132 + f];
#pragma unroll
    for (int ee = 0; ee < 4; ++ee) {
      float4 av = As4[f * 32 + sub + (ee << 3)];
      acc[ee].x += ph * av.x;
      acc[ee].y += ph * av.y;
      acc[ee].z += ph * av.z;
      acc[ee].w += ph * av.w;
    }
  }
  float4* og = (float4*)(out + ((size_t)(bh * L + row)) * D);
  const float4* bg = (const float4*)bproj;
#pragma unroll
  for (int ee = 0; ee < 4; ++ee) {
    int c = sub + (ee << 3);
    float4 oo = og[c];
    float4 bb = bg[c];
    oo.x += acc[ee].x * rden + bb.x;
    oo.y += acc[ee].y * rden + bb.y;
    oo.z += acc[ee].z * rden + bb.z;
    oo.w += acc[ee].w * rden + bb.w;
    og[c] = oo;
  }
}

extern "C" void kernel_launch(void* const* d_in, const int* in_sizes, int n_in,
                              void* d_out, int out_size, void* d_ws, size_t ws_size,
                              hipStream_t stream) {
  const float* q = (const float*)d_in[0];
  const float* k = (const float*)d_in[1];
  const float* v = (const float*)d_in[2];
  const float* w = (const float*)d_in[3];
  const float* b = (const float*)d_in[4];
  float* out = (float*)d_out;
  float* ws = (float*)d_ws;
  float* qb    = ws + QB_OFF;
  float* kb    = ws + KB_OFF;
  int*   lut   = (int*)(ws + LUT_OFF);
  float* kvsum = ws + KV_OFF;
  float* ksum  = ws + KS_OFF;
  float* A     = ws + A_OFF;
  unsigned short* khi  = (unsigned short*)(ws + KHI_OFF);
  unsigned short* klo  = (unsigned short*)(ws + KLO_OFF);
  unsigned short* vthi = (unsigned short*)(ws + VTHI_OFF);
  unsigned short* vtlo = (unsigned short*)(ws + VTLO_OFF);

  hipFuncSetAttribute(reinterpret_cast<const void*>(k_attn),
                      hipFuncAttributeMaxDynamicSharedMemorySize, 81920);
  hipFuncSetAttribute(reinterpret_cast<const void*>(k_linear_out),
                      hipFuncAttributeMaxDynamicSharedMemorySize, 82944);

  hipMemsetAsync(kvsum, 0, (size_t)(524288 + 4096) * sizeof(float), stream);

  k_prep      <<<dim3(BH * NB), dim3(256), 0, stream>>>(q, k, v, qb, kb, khi, klo, vthi, vtlo);
  k_scores_topk<<<dim3(BH),     dim3(256), 0, stream>>>(qb, kb, lut);
  k_attn      <<<dim3(NB, BH),  dim3(256), 81920, stream>>>(q, khi, klo, vthi, vtlo, lut, out);
  k_kvsum     <<<dim3(BH * 16), dim3(256), 0, stream>>>(k, v, kvsum, ksum);
  k_projA     <<<dim3(4, BH),   dim3(256), 0, stream>>>(kvsum, w, A);
  k_linear_out<<<dim3(64, BH),  dim3(256), 82944, stream>>>(q, A, ksum, b, out);
}

// Round 3
// 331.190 us; speedup vs baseline: 1.7860x; 1.2976x over previous
//
#include <hip/hip_runtime.h>
#include <math.h>

// SparseLinearAttention R3 — MFMA kvsum + XCD swizzle, MI355X (gfx950)
// B=2 H=16 L=2048 D=128, 64-row blocks, top-4 of 32 k-blocks per q-block.
static constexpr int BH   = 32;
static constexpr int L    = 2048;
static constexpr int D    = 128;
static constexpr int NB   = 32;
static constexpr int TOPK = 4;

// workspace layout (float slots); total 34,349,056 floats = 137.4 MB
static constexpr size_t QB_OFF    = 0;          // 32*32*128
static constexpr size_t KB_OFF    = 131072;
static constexpr size_t LUT_OFF   = 262144;     // int[32*32*4]
static constexpr size_t KS_OFF    = 266240;     // 32*128
static constexpr size_t A_OFF     = 270336;     // 32*128*128
static constexpr size_t PART_OFF  = 794624;     // 512*128*128 split-K partials
static constexpr size_t KHI_OFF   = 9183232;    // bf16 32*2048*128 (4.19M float slots)
static constexpr size_t KLO_OFF   = 13377536;
static constexpr size_t VTHI_OFF  = 17571840;   // [bid][128][64] transposed v
static constexpr size_t VTLO_OFF  = 21766144;
static constexpr size_t PHITH_OFF = 25960448;   // [bid][128][64] transposed phi_k
static constexpr size_t PHITL_OFF = 30154752;

typedef __attribute__((ext_vector_type(8))) short short8;
typedef __attribute__((ext_vector_type(4))) float f32x4;

__device__ __forceinline__ unsigned short f2bf(float x) {   // RNE fp32->bf16
  unsigned u = __float_as_uint(x);
  u += 0x7fffu + ((u >> 16) & 1u);
  return (unsigned short)(u >> 16);
}
__device__ __forceinline__ float bf2f(unsigned short h) {
  return __uint_as_float(((unsigned)h) << 16);
}
__device__ __forceinline__ f32x4 mfma16(short8 a, short8 b, f32x4 c) {
  return __builtin_amdgcn_mfma_f32_16x16x32_bf16(a, b, c, 0, 0, 0);
}
__device__ __forceinline__ void gl_lds16(const void* g, void* l) {
  __builtin_amdgcn_global_load_lds(
      (const __attribute__((address_space(1))) unsigned int*)g,
      (__attribute__((address_space(3))) unsigned int*)l, 16, 0, 0);
}

// ---------------- K0: means + k->bf16 hi/lo + phi_k softmax + V/phi transpose
__global__ __launch_bounds__(256) void k_prep(
    const float* __restrict__ q, const float* __restrict__ k, const float* __restrict__ v,
    float* __restrict__ qb, float* __restrict__ kb,
    unsigned short* __restrict__ khi, unsigned short* __restrict__ klo,
    unsigned short* __restrict__ vthi, unsigned short* __restrict__ vtlo,
    unsigned short* __restrict__ phith, unsigned short* __restrict__ phitl,
    float* __restrict__ ksum) {
  extern __shared__ float smp[];
  float* Vs   = smp;           // 8192 f, swizzled (quad ^= (row>>2)&7)
  float* Ps   = smp + 8192;    // 8192 f, phi_k fp32, same swizzle
  float* part = smp + 16384;   // 1024 f
  int bid = blockIdx.x;        // bh*NB + kblk
  int t = threadIdx.x;
  size_t rb = (size_t)bid * 64 * D;
  int c = t & 31, g = t >> 5;
  // stage v swizzled
  const float4* v4 = (const float4*)(v + rb);
  float4* Vs4 = (float4*)Vs;
  float4* Ps4 = (float4*)Ps;
#pragma unroll
  for (int it = 0; it < 8; ++it) {
    int p = t + 256 * it;
    int row = p >> 5, cq = p & 31;
    Vs4[row * 32 + (cq ^ ((row >> 2) & 7))] = v4[p];
  }
  // q mean
  float4 qs = {0.f, 0.f, 0.f, 0.f};
#pragma unroll
  for (int it = 0; it < 8; ++it) {
    int row = g + 8 * it;
    float4 xv = *(const float4*)(q + rb + (size_t)row * D + 4 * c);
    qs.x += xv.x; qs.y += xv.y; qs.z += xv.z; qs.w += xv.w;
  }
  ((float4*)part)[g * 32 + c] = qs;
  __syncthreads();
  if (t < 128) {
    float s = 0.f;
#pragma unroll
    for (int gg = 0; gg < 8; ++gg) s += part[gg * 128 + t];
    qb[(size_t)bid * D + t] = s * (1.f / 64.f);
  }
  __syncthreads();
  // k: convert hi/lo + mean + row softmax (row owned by 32 lanes, shfl widths<=16)
  float4 ks = {0.f, 0.f, 0.f, 0.f};
#pragma unroll
  for (int it = 0; it < 8; ++it) {
    int row = g + 8 * it;
    size_t off = rb + (size_t)row * D + 4 * c;
    float4 xv = *(const float4*)(k + off);
    ushort4 h, l;
    h.x = f2bf(xv.x); l.x = f2bf(xv.x - bf2f(h.x));
    h.y = f2bf(xv.y); l.y = f2bf(xv.y - bf2f(h.y));
    h.z = f2bf(xv.z); l.z = f2bf(xv.z - bf2f(h.z));
    h.w = f2bf(xv.w); l.w = f2bf(xv.w - bf2f(h.w));
    *(ushort4*)(khi + off) = h;
    *(ushort4*)(klo + off) = l;
    ks.x += xv.x; ks.y += xv.y; ks.z += xv.z; ks.w += xv.w;
    // row softmax
    float mx = fmaxf(fmaxf(xv.x, xv.y), fmaxf(xv.z, xv.w));
    mx = fmaxf(mx, __shfl_xor(mx, 1));
    mx = fmaxf(mx, __shfl_xor(mx, 2));
    mx = fmaxf(mx, __shfl_xor(mx, 4));
    mx = fmaxf(mx, __shfl_xor(mx, 8));
    mx = fmaxf(mx, __shfl_xor(mx, 16));
    float e0 = __expf(xv.x - mx), e1 = __expf(xv.y - mx);
    float e2 = __expf(xv.z - mx), e3 = __expf(xv.w - mx);
    float es = e0 + e1 + e2 + e3;
    es += __shfl_xor(es, 1);
    es += __shfl_xor(es, 2);
    es += __shfl_xor(es, 4);
    es += __shfl_xor(es, 8);
    es += __shfl_xor(es, 16);
    float inv = 1.f / es;
    Ps4[row * 32 + (c ^ ((row >> 2) & 7))] =
        make_float4(e0 * inv, e1 * inv, e2 * inv, e3 * inv);
  }
  ((float4*)part)[g * 32 + c] = ks;
  __syncthreads();
  if (t < 128) {
    float s = 0.f;
#pragma unroll
    for (int gg = 0; gg < 8; ++gg) s += part[gg * 128 + t];
    kb[(size_t)bid * D + t] = s * (1.f / 64.f);
  }
  __syncthreads();    // Vs + Ps complete
  // emit vt and phit hi/lo: [bid][d][j], rows of 64 bf16 (128B)
  size_t tb = (size_t)bid * 8192;
#pragma unroll
  for (int pp = 0; pp < 4; ++pp) {
    int d = 32 * pp + (t >> 3);
    int jc = t & 7;
    unsigned hs[8], ls[8], phs[8], pls[8];
#pragma unroll
    for (int i = 0; i < 8; ++i) {
      int j = jc * 8 + i;
      int idx = j * 128 + (d ^ (j & 28));
      float x = Vs[idx];
      unsigned short hh = f2bf(x);
      hs[i] = hh; ls[i] = f2bf(x - bf2f(hh));
      float px = Ps[idx];
      unsigned short phh = f2bf(px);
      phs[i] = phh; pls[i] = f2bf(px - bf2f(phh));
    }
    int4 hw, lw, pw, qw;
    hw.x = (int)(hs[0] | (hs[1] << 16)); hw.y = (int)(hs[2] | (hs[3] << 16));
    hw.z = (int)(hs[4] | (hs[5] << 16)); hw.w = (int)(hs[6] | (hs[7] << 16));
    lw.x = (int)(ls[0] | (ls[1] << 16)); lw.y = (int)(ls[2] | (ls[3] << 16));
    lw.z = (int)(ls[4] | (ls[5] << 16)); lw.w = (int)(ls[6] | (ls[7] << 16));
    pw.x = (int)(phs[0] | (phs[1] << 16)); pw.y = (int)(phs[2] | (phs[3] << 16));
    pw.z = (int)(phs[4] | (phs[5] << 16)); pw.w = (int)(phs[6] | (phs[7] << 16));
    qw.x = (int)(pls[0] | (pls[1] << 16)); qw.y = (int)(pls[2] | (pls[3] << 16));
    qw.z = (int)(pls[4] | (pls[5] << 16)); qw.w = (int)(pls[6] | (pls[7] << 16));
    *(int4*)(vthi  + tb + (size_t)d * 64 + jc * 8) = hw;
    *(int4*)(vtlo  + tb + (size_t)d * 64 + jc * 8) = lw;
    *(int4*)(phith + tb + (size_t)d * 64 + jc * 8) = pw;
    *(int4*)(phitl + tb + (size_t)d * 64 + jc * 8) = qw;
  }
  // ksum partial: column sums of phi over this block's 64 rows
  if (t < 128) {
    float s = 0.f;
#pragma unroll
    for (int row = 0; row < 64; ++row) s += Ps[row * 128 + (t ^ (row & 28))];
    atomicAdd(&ksum[(size_t)(bid >> 5) * D + t], s);
  }
}

// ---------------- K2: 32x32 block scores + top-4 per row ----------------
__global__ __launch_bounds__(256) void k_scores_topk(
    const float* __restrict__ qb, const float* __restrict__ kb, int* __restrict__ lut) {
  __shared__ float qs[NB * D];
  __shared__ float ks[NB * 132];
  __shared__ float sc[NB * 33];
  int bh = blockIdx.x, t = threadIdx.x;
  const float4* qg = (const float4*)(qb + (size_t)bh * NB * D);
  const float4* kg = (const float4*)(kb + (size_t)bh * NB * D);
  float4* qs4 = (float4*)qs;
  float4* ks4 = (float4*)ks;
#pragma unroll
  for (int it = 0; it < 4; ++it) {
    int p = t + 256 * it;
    int row = p >> 5, c = p & 31;
    qs4[p] = qg[p];
    ks4[row * 33 + c] = kg[p];
  }
  __syncthreads();
#pragma unroll
  for (int ss = 0; ss < 4; ++ss) {
    int idx = t + 256 * ss;
    int qr = idx >> 5, kc = idx & 31;
    float acc = 0.f;
#pragma unroll
    for (int c = 0; c < 32; ++c) {
      float4 a = qs4[qr * 32 + c];
      float4 b = ks4[kc * 33 + c];
      acc += a.x * b.x + a.y * b.y + a.z * b.z + a.w * b.w;
    }
    sc[qr * 33 + kc] = acc;
  }
  __syncthreads();
  if (t < NB) {    // lowest index wins ties, like lax.top_k
    unsigned mask = 0;
    for (int s = 0; s < TOPK; ++s) {
      float best = -INFINITY; int bi = 0;
      for (int j = 0; j < NB; ++j) {
        float vv = sc[t * 33 + j];
        if (!((mask >> j) & 1u) && vv > best) { best = vv; bi = j; }
      }
      mask |= 1u << bi;
      lut[((size_t)(bh * NB) + t) * TOPK + s] = bi;
    }
  }
}

// ---------------- K3: MFMA flash sparse attention (XCD-chunked swizzle) -----
__global__ __launch_bounds__(256) void k_attn(
    const float* __restrict__ q,
    const unsigned short* __restrict__ khi, const unsigned short* __restrict__ klo,
    const unsigned short* __restrict__ vthi, const unsigned short* __restrict__ vtlo,
    const int* __restrict__ lut, float* __restrict__ out) {
  extern __shared__ char sm[];
  char* KsH = sm;                 // 16KB each
  char* KsL = sm + 16384;
  char* VsH = sm + 32768;
  char* VsL = sm + 49152;
  // XCD-chunked bijective swizzle (1024 = 8 XCD * 128): each XCD owns 4 bh's
  int f = blockIdx.x;
  int n = ((f & 7) << 7) | (f >> 3);
  int qblk = n & 31, bh = n >> 5;
  int t = threadIdx.x, lane = t & 63, w = t >> 6;
  char* PwH = sm + 65536 + w * 4096;   // per-wave P: 16x64 bf16 hi (2KB) + lo
  char* PwL = PwH + 2048;
  int lr = lane & 15, lg = lane >> 4;
  const float scale = 0.088388347648318447f;   // 1/sqrt(128)

  short8 qh[4], ql[4];
  const float* qrow = q + ((size_t)bh * L + (size_t)qblk * 64 + 16 * w + lr) * D;
#pragma unroll
  for (int s = 0; s < 4; ++s) {
    float4 x0 = *(const float4*)(qrow + 32 * s + 8 * lg);
    float4 x1 = *(const float4*)(qrow + 32 * s + 8 * lg + 4);
    float xs[8] = {x0.x, x0.y, x0.z, x0.w, x1.x, x1.y, x1.z, x1.w};
    short8 hv, lv;
#pragma unroll
    for (int i = 0; i < 8; ++i) {
      unsigned short h = f2bf(xs[i]);
      hv[i] = (short)h;
      lv[i] = (short)f2bf(xs[i] - bf2f(h));
    }
    qh[s] = hv; ql[s] = lv;
  }

  f32x4 oacc[8];
#pragma unroll
  for (int i = 0; i < 8; ++i) oacc[i] = (f32x4){0.f, 0.f, 0.f, 0.f};
  float mrun = -INFINITY, lrun = 0.f;

  const int* lp = lut + ((size_t)bh * NB + qblk) * TOPK;
  for (int itb = 0; itb < TOPK; ++itb) {
    int kblk = lp[itb];
    __syncthreads();
    {
      const char* kbh = (const char*)(khi + ((size_t)bh * L + (size_t)kblk * 64) * D);
      const char* kbl = (const char*)(klo + ((size_t)bh * L + (size_t)kblk * 64) * D);
      const char* vbh = (const char*)(vthi + ((size_t)(bh * NB + kblk)) * 8192);
      const char* vbl = (const char*)(vtlo + ((size_t)(bh * NB + kblk)) * 8192);
#pragma unroll
      for (int jj = 0; jj < 4; ++jj) {
        int ib = 4 * w + jj;
        {  // K tiles: 256B rows, 4 rows / instr
          int lrow = 4 * ib + (lane >> 4);
          int soff = lrow * 256 + (((lane & 15) ^ (lrow & 7)) << 4);
          gl_lds16(kbh + soff, KsH + ib * 1024);
          gl_lds16(kbl + soff, KsL + ib * 1024);
        }
        {  // Vt tiles: 128B rows, 8 rows / instr
          int lrow = 8 * ib + (lane >> 3);
          int soff = lrow * 128 + (((lane & 7) ^ (lrow & 7)) << 4);
          gl_lds16(vbh + soff, VsH + ib * 1024);
          gl_lds16(vbl + soff, VsL + ib * 1024);
        }
      }
    }
    __syncthreads();
    // ---- QK^T
    f32x4 sacc[4];
#pragma unroll
    for (int i = 0; i < 4; ++i) sacc[i] = (f32x4){0.f, 0.f, 0.f, 0.f};
#pragma unroll
    for (int s = 0; s < 4; ++s) {
#pragma unroll
      for (int tk = 0; tk < 4; ++tk) {
        int krow = 16 * tk + lr;
        int off = krow * 256 + (((4 * s + lg) ^ (krow & 7)) << 4);
        short8 kH = *(const short8*)(KsH + off);
        short8 kL = *(const short8*)(KsL + off);
        sacc[tk] = mfma16(kH, qh[s], sacc[tk]);
        sacc[tk] = mfma16(kL, qh[s], sacc[tk]);
        sacc[tk] = mfma16(kH, ql[s], sacc[tk]);
      }
    }
    // ---- online softmax (lane owns q-row lr)
    float mloc = -INFINITY;
#pragma unroll
    for (int tk = 0; tk < 4; ++tk)
#pragma unroll
      for (int r = 0; r < 4; ++r) mloc = fmaxf(mloc, sacc[tk][r]);
    mloc = fmaxf(mloc, __shfl_xor(mloc, 16));
    mloc = fmaxf(mloc, __shfl_xor(mloc, 32));
    float mnew = fmaxf(mrun, mloc * scale);
    float alpha = __expf(mrun - mnew);
    float lloc = 0.f;
#pragma unroll
    for (int tk = 0; tk < 4; ++tk) {
      unsigned ph[4], pl[4];
#pragma unroll
      for (int r = 0; r < 4; ++r) {
        float pf = __expf(sacc[tk][r] * scale - mnew);
        lloc += pf;
        unsigned short hh = f2bf(pf);
        ph[r] = hh; pl[r] = f2bf(pf - bf2f(hh));
      }
      int j0b = 32 * tk + 8 * lg;
      int slot16 = j0b >> 4, half = (j0b >> 3) & 1;
      int off = lr * 128 + ((slot16 ^ (lr & 7)) << 4) + half * 8;
      *(int2*)(PwH + off) = make_int2((int)(ph[0] | (ph[1] << 16)),
                                      (int)(ph[2] | (ph[3] << 16)));
      *(int2*)(PwL + off) = make_int2((int)(pl[0] | (pl[1] << 16)),
                                      (int)(pl[2] | (pl[3] << 16)));
    }
    lloc += __shfl_xor(lloc, 16);
    lloc += __shfl_xor(lloc, 32);
    lrun = lrun * alpha + lloc;
    mrun = mnew;
    float ar[4];
#pragma unroll
    for (int r = 0; r < 4; ++r) ar[r] = __shfl(alpha, 4 * lg + r);
#pragma unroll
    for (int tv = 0; tv < 8; ++tv)
#pragma unroll
      for (int r = 0; r < 4; ++r) oacc[tv][r] *= ar[r];
    // ---- PV
#pragma unroll
    for (int ks = 0; ks < 2; ++ks) {
      int poff = lr * 128 + (((lg + 4 * ks) ^ (lr & 7)) << 4);
      short8 pH = *(const short8*)(PwH + poff);
      short8 pL = *(const short8*)(PwL + poff);
#pragma unroll
      for (int tv = 0; tv < 8; ++tv) {
        int vrow = 16 * tv + lr;
        int voff = vrow * 128 + (((lg + 4 * ks) ^ (vrow & 7)) << 4);
        short8 vH = *(const short8*)(VsH + voff);
        short8 vL = *(const short8*)(VsL + voff);
        oacc[tv] = mfma16(pH, vH, oacc[tv]);
        oacc[tv] = mfma16(pL, vH, oacc[tv]);
        oacc[tv] = mfma16(pH, vL, oacc[tv]);
      }
    }
  }
  float rinv[4];
#pragma unroll
  for (int r = 0; r < 4; ++r) rinv[r] = 1.f / __shfl(lrun, 4 * lg + r);
  float* ob = out + ((size_t)bh * L + (size_t)qblk * 64 + 16 * w) * D;
#pragma unroll
  for (int tv = 0; tv < 8; ++tv)
#pragma unroll
    for (int r = 0; r < 4; ++r)
      ob[(size_t)(4 * lg + r) * D + 16 * tv + lr] = oacc[tv][r] * rinv[r];
}

// ---------------- K4: kvsumT[e][d] partials via MFMA (no LDS, no atomics) ---
// blockIdx = (slice 0..15, bh). Each block: 128 rows (2 kblocks), full 128x128
// partial in registers. A = vt (e x l), B = phit (l x d), C row = e, col = d.
__global__ __launch_bounds__(256) void k_kvmm(
    const unsigned short* __restrict__ vthi, const unsigned short* __restrict__ vtlo,
    const unsigned short* __restrict__ phith, const unsigned short* __restrict__ phitl,
    float* __restrict__ part) {
  int slice = blockIdx.x, bh = blockIdx.y;
  int t = threadIdx.x, lane = t & 63, w = t >> 6;
  int lr = lane & 15, lg = lane >> 4;
  f32x4 acc[2][8];
#pragma unroll
  for (int et = 0; et < 2; ++et)
#pragma unroll
    for (int dt = 0; dt < 8; ++dt) acc[et][dt] = (f32x4){0.f, 0.f, 0.f, 0.f};
#pragma unroll
  for (int ks = 0; ks < 4; ++ks) {
    int kblk = 2 * slice + (ks >> 1);
    int li = 32 * (ks & 1);
    size_t base = ((size_t)(bh * NB + kblk)) * 8192 + li + 8 * lg;
    short8 aH[2], aL[2];
#pragma unroll
    for (int et = 0; et < 2; ++et) {
      int e = 32 * w + 16 * et + lr;
      aH[et] = *(const short8*)(vthi + base + (size_t)e * 64);
      aL[et] = *(const short8*)(vtlo + base + (size_t)e * 64);
    }
#pragma unroll
    for (int dt = 0; dt < 8; ++dt) {
      int d = 16 * dt + lr;
      short8 bH = *(const short8*)(phith + base + (size_t)d * 64);
      short8 bL = *(const short8*)(phitl + base + (size_t)d * 64);
#pragma unroll
      for (int et = 0; et < 2; ++et) {
        acc[et][dt] = mfma16(aH[et], bH, acc[et][dt]);
        acc[et][dt] = mfma16(aL[et], bH, acc[et][dt]);
        acc[et][dt] = mfma16(aH[et], bL, acc[et][dt]);
      }
    }
  }
  float* pb = part + ((size_t)(bh * 16 + slice)) * 16384;
#pragma unroll
  for (int et = 0; et < 2; ++et)
#pragma unroll
    for (int dt = 0; dt < 8; ++dt)
#pragma unroll
      for (int r = 0; r < 4; ++r)
        pb[(size_t)(32 * w + 16 * et + 4 * lg + r) * 128 + 16 * dt + lr] =
            acc[et][dt][r];
}

// ---------------- K5: A[d][j] = sum_e kvsumT[e][d] * w[j][e]; 16-part reduce
__global__ __launch_bounds__(256) void k_projA(
    const float* __restrict__ part, const float* __restrict__ w, float* __restrict__ A) {
  extern __shared__ float smA[];
  float* wts   = smA;            // 16384 f, swizzled
  float* kvred = smA + 16384;    // 128 x 32 f
  int dquad = blockIdx.x, bh = blockIdx.y;
  int t = threadIdx.x;
  const float4* wg = (const float4*)w;
#pragma unroll
  for (int it = 0; it < 16; ++it) {
    int p4 = t + 256 * it;
    int j = p4 >> 5, ebase = (p4 & 31) << 2;
    float4 val = wg[p4];
    wts[(ebase + 0) * D + ((j + ebase + 0) & 127)] = val.x;
    wts[(ebase + 1) * D + ((j + ebase + 1) & 127)] = val.y;
    wts[(ebase + 2) * D + ((j + ebase + 2) & 127)] = val.z;
    wts[(ebase + 3) * D + ((j + ebase + 3) & 127)] = val.w;
  }
  // reduce 16 partials for this dquad's 128x32 sub-block
#pragma unroll
  for (int u = 0; u < 4; ++u) {
    int f4id = t + 256 * u;          // 1024 float4 = 128 e x 8
    int e = f4id >> 3, dl4 = f4id & 7;
    float4 acc4 = {0.f, 0.f, 0.f, 0.f};
#pragma unroll
    for (int s = 0; s < 16; ++s) {
      float4 p = *(const float4*)(part + ((size_t)(bh * 16 + s)) * 16384 +
                                  (size_t)e * 128 + dquad * 32 + dl4 * 4);
      acc4.x += p.x; acc4.y += p.y; acc4.z += p.z; acc4.w += p.w;
    }
    *(float4*)(kvred + e * 32 + dl4 * 4) = acc4;
  }
  __syncthreads();
  int j = t & 127, dh = t >> 7;
  int dbase = dquad * 32 + dh * 16;
  float acc[16];
#pragma unroll
  for (int u = 0; u < 16; ++u) acc[u] = 0.f;
  for (int e = 0; e < D; ++e) {
    float wv = wts[e * D + ((j + e) & 127)];
#pragma unroll
    for (int dd = 0; dd < 16; ++dd)
      acc[dd] += kvred[e * 32 + dh * 16 + dd] * wv;
  }
#pragma unroll
  for (int dd = 0; dd < 16; ++dd)
    A[((size_t)(bh * D + dbase + dd)) * D + j] = acc[dd];
}

// ---------------- K6: out += (softmax(q) @ A)/den + b_proj ----------------
__global__ __launch_bounds__(256) void k_linear_out(
    const float* __restrict__ q, const float* __restrict__ A,
    const float* __restrict__ ksum, const float* __restrict__ bproj,
    float* __restrict__ out) {
  extern __shared__ float smf[];
  float* As    = smf;
  float* phis  = smf + 16384;
  float* ksums = smf + 16384 + 32 * 132;
  int rb = blockIdx.x, bh = blockIdx.y;
  int t = threadIdx.x;
  int r = t >> 3, sub = t & 7;
  const float4* Ag = (const float4*)(A + (size_t)bh * D * D);
  float4* As4 = (float4*)As;
#pragma unroll
  for (int it = 0; it < 16; ++it) {
    int p = t + 256 * it;
    As4[p] = Ag[p];
  }
  if (t < D) ksums[t] = ksum[bh * D + t];
  int row = rb * 32 + r;
  const float4* qr4 = (const float4*)(q + ((size_t)(bh * L + row)) * D) + sub * 4;
  float x[16];
  {
    float4 a0 = qr4[0], a1 = qr4[1], a2 = qr4[2], a3 = qr4[3];
    x[0]=a0.x; x[1]=a0.y; x[2]=a0.z; x[3]=a0.w;
    x[4]=a1.x; x[5]=a1.y; x[6]=a1.z; x[7]=a1.w;
    x[8]=a2.x; x[9]=a2.y; x[10]=a2.z; x[11]=a2.w;
    x[12]=a3.x; x[13]=a3.y; x[14]=a3.z; x[15]=a3.w;
  }
  float mx = -INFINITY;
#pragma unroll
  for (int u = 0; u < 16; ++u) mx = fmaxf(mx, x[u]);
  mx = fmaxf(mx, __shfl_xor(mx, 1));
  mx = fmaxf(mx, __shfl_xor(mx, 2));
  mx = fmaxf(mx, __shfl_xor(mx, 4));
  float es = 0.f;
#pragma unroll
  for (int u = 0; u < 16; ++u) { x[u] = __expf(x[u] - mx); es += x[u]; }
  es += __shfl_xor(es, 1);
  es += __shfl_xor(es, 2);
  es += __shfl_xor(es, 4);
  float inv = 1.f / es;
  __syncthreads();
  float dloc = 0.f;
#pragma unroll
  for (int u = 0; u < 16; ++u) {
    float ph = x[u] * inv;
    phis[r * 132 + sub * 16 + u] = ph;
    dloc += ph * ksums[sub * 16 + u];
  }
  dloc += __shfl_xor(dloc, 1);
  dloc += __shfl_xor(dloc, 2);
  dloc += __shfl_xor(dloc, 4);
  float rden = 1.f / (1e-5f + dloc);
  __syncthreads();
  float4 acc[4];
#pragma unroll
  for (int ee = 0; ee < 4; ++ee) { acc[ee].x = 0.f; acc[ee].y = 0.f; acc[ee].z = 0.f; acc[ee].w = 0.f; }
  for (int f = 0; f < D; ++f) {
    float ph = phis[r * 132 + f];
#pragma unroll
    for (int ee = 0; ee < 4; ++ee) {
      float4 av = As4[f * 32 + sub + (ee << 3)];
      acc[ee].x += ph * av.x;
      acc[ee].y += ph * av.y;
      acc[ee].z += ph * av.z;
      acc[ee].w += ph * av.w;
    }
  }
  float4* og = (float4*)(out + ((size_t)(bh * L + row)) * D);
  const float4* bg = (const float4*)bproj;
#pragma unroll
  for (int ee = 0; ee < 4; ++ee) {
    int c = sub + (ee << 3);
    float4 oo = og[c];
    float4 bb = bg[c];
    oo.x += acc[ee].x * rden + bb.x;
    oo.y += acc[ee].y * rden + bb.y;
    oo.z += acc[ee].z * rden + bb.z;
    oo.w += acc[ee].w * rden + bb.w;
    og[c] = oo;
  }
}

extern "C" void kernel_launch(void* const* d_in, const int* in_sizes, int n_in,
                              void* d_out, int out_size, void* d_ws, size_t ws_size,
                              hipStream_t stream) {
  const float* q = (const float*)d_in[0];
  const float* k = (const float*)d_in[1];
  const float* v = (const float*)d_in[2];
  const float* w = (const float*)d_in[3];
  const float* b = (const float*)d_in[4];
  float* out = (float*)d_out;
  float* ws = (float*)d_ws;
  float* qb    = ws + QB_OFF;
  float* kb    = ws + KB_OFF;
  int*   lut   = (int*)(ws + LUT_OFF);
  float* ksum  = ws + KS_OFF;
  float* A     = ws + A_OFF;
  float* partb = ws + PART_OFF;
  unsigned short* khi   = (unsigned short*)(ws + KHI_OFF);
  unsigned short* klo   = (unsigned short*)(ws + KLO_OFF);
  unsigned short* vthi  = (unsigned short*)(ws + VTHI_OFF);
  unsigned short* vtlo  = (unsigned short*)(ws + VTLO_OFF);
  unsigned short* phith = (unsigned short*)(ws + PHITH_OFF);
  unsigned short* phitl = (unsigned short*)(ws + PHITL_OFF);

  hipFuncSetAttribute(reinterpret_cast<const void*>(k_prep),
                      hipFuncAttributeMaxDynamicSharedMemorySize, 69632);
  hipFuncSetAttribute(reinterpret_cast<const void*>(k_attn),
                      hipFuncAttributeMaxDynamicSharedMemorySize, 81920);
  hipFuncSetAttribute(reinterpret_cast<const void*>(k_projA),
                      hipFuncAttributeMaxDynamicSharedMemorySize, 81920);
  hipFuncSetAttribute(reinterpret_cast<const void*>(k_linear_out),
                      hipFuncAttributeMaxDynamicSharedMemorySize, 82944);

  hipMemsetAsync(ksum, 0, 4096 * sizeof(float), stream);

  k_prep       <<<dim3(BH * NB), dim3(256), 69632, stream>>>(
      q, k, v, qb, kb, khi, klo, vthi, vtlo, phith, phitl, ksum);
  k_scores_topk<<<dim3(BH),      dim3(256), 0, stream>>>(qb, kb, lut);
  k_attn       <<<dim3(NB * BH), dim3(256), 81920, stream>>>(
      q, khi, klo, vthi, vtlo, lut, out);
  k_kvmm       <<<dim3(16, BH),  dim3(256), 0, stream>>>(
      vthi, vtlo, phith, phitl, partb);
  k_projA      <<<dim3(4, BH),   dim3(256), 81920, stream>>>(partb, w, A);
  k_linear_out <<<dim3(64, BH),  dim3(256), 82944, stream>>>(q, A, ksum, b, out);
}

// Round 6
// 299.322 us; speedup vs baseline: 1.9761x; 1.1065x over previous
//
#include <hip/hip_runtime.h>
#include <math.h>

// SparseLinearAttention R4 — MFMA linear-out (zero LDS), MI355X (gfx950)
// B=2 H=16 L=2048 D=128, 64-row blocks, top-4 of 32 k-blocks per q-block.
static constexpr int BH   = 32;
static constexpr int L    = 2048;
static constexpr int D    = 128;
static constexpr int NB   = 32;
static constexpr int TOPK = 4;

// workspace layout (float slots)
static constexpr size_t QB_OFF    = 0;          // 32*32*128
static constexpr size_t KB_OFF    = 131072;
static constexpr size_t LUT_OFF   = 262144;     // int[32*32*4]
static constexpr size_t KS_OFF    = 266240;     // 32*128
static constexpr size_t ATHI_OFF  = 270336;     // bf16 At[bh][j][d] 32*128*128
static constexpr size_t ATLO_OFF  = 532480;
static constexpr size_t PART_OFF  = 794624;     // 512*128*128 split-K partials
static constexpr size_t KHI_OFF   = 9183232;    // bf16 32*2048*128
static constexpr size_t KLO_OFF   = 13377536;
static constexpr size_t VTHI_OFF  = 17571840;   // [bid][128][64] transposed v
static constexpr size_t VTLO_OFF  = 21766144;
static constexpr size_t PHITH_OFF = 25960448;   // [bid][128][64] transposed phi_k
static constexpr size_t PHITL_OFF = 30154752;

typedef __attribute__((ext_vector_type(8))) short short8;
typedef __attribute__((ext_vector_type(4))) float f32x4;

__device__ __forceinline__ unsigned short f2bf(float x) {   // RNE fp32->bf16
  unsigned u = __float_as_uint(x);
  u += 0x7fffu + ((u >> 16) & 1u);
  return (unsigned short)(u >> 16);
}
__device__ __forceinline__ float bf2f(unsigned short h) {
  return __uint_as_float(((unsigned)h) << 16);
}
__device__ __forceinline__ f32x4 mfma16(short8 a, short8 b, f32x4 c) {
  return __builtin_amdgcn_mfma_f32_16x16x32_bf16(a, b, c, 0, 0, 0);
}
__device__ __forceinline__ void gl_lds16(const void* g, void* l) {
  __builtin_amdgcn_global_load_lds(
      (const __attribute__((address_space(1))) unsigned int*)g,
      (__attribute__((address_space(3))) unsigned int*)l, 16, 0, 0);
}

// ---------------- K0: means + k->bf16 hi/lo + phi_k softmax + V/phi transpose
__global__ __launch_bounds__(256) void k_prep(
    const float* __restrict__ q, const float* __restrict__ k, const float* __restrict__ v,
    float* __restrict__ qb, float* __restrict__ kb,
    unsigned short* __restrict__ khi, unsigned short* __restrict__ klo,
    unsigned short* __restrict__ vthi, unsigned short* __restrict__ vtlo,
    unsigned short* __restrict__ phith, unsigned short* __restrict__ phitl,
    float* __restrict__ ksum) {
  extern __shared__ float smp[];
  float* Vs   = smp;           // 8192 f, swizzled (quad ^= (row>>2)&7)
  float* Ps   = smp + 8192;    // 8192 f, phi_k fp32, same swizzle
  float* part = smp + 16384;   // 1024 f
  int bid = blockIdx.x;        // bh*NB + kblk
  int t = threadIdx.x;
  size_t rb = (size_t)bid * 64 * D;
  int c = t & 31, g = t >> 5;
  const float4* v4 = (const float4*)(v + rb);
  float4* Vs4 = (float4*)Vs;
  float4* Ps4 = (float4*)Ps;
#pragma unroll
  for (int it = 0; it < 8; ++it) {
    int p = t + 256 * it;
    int row = p >> 5, cq = p & 31;
    Vs4[row * 32 + (cq ^ ((row >> 2) & 7))] = v4[p];
  }
  // q mean
  float4 qs = {0.f, 0.f, 0.f, 0.f};
#pragma unroll
  for (int it = 0; it < 8; ++it) {
    int row = g + 8 * it;
    float4 xv = *(const float4*)(q + rb + (size_t)row * D + 4 * c);
    qs.x += xv.x; qs.y += xv.y; qs.z += xv.z; qs.w += xv.w;
  }
  ((float4*)part)[g * 32 + c] = qs;
  __syncthreads();
  if (t < 128) {
    float s = 0.f;
#pragma unroll
    for (int gg = 0; gg < 8; ++gg) s += part[gg * 128 + t];
    qb[(size_t)bid * D + t] = s * (1.f / 64.f);
  }
  __syncthreads();
  // k: convert hi/lo + mean + row softmax
  float4 ks = {0.f, 0.f, 0.f, 0.f};
#pragma unroll
  for (int it = 0; it < 8; ++it) {
    int row = g + 8 * it;
    size_t off = rb + (size_t)row * D + 4 * c;
    float4 xv = *(const float4*)(k + off);
    ushort4 h, l;
    h.x = f2bf(xv.x); l.x = f2bf(xv.x - bf2f(h.x));
    h.y = f2bf(xv.y); l.y = f2bf(xv.y - bf2f(h.y));
    h.z = f2bf(xv.z); l.z = f2bf(xv.z - bf2f(h.z));
    h.w = f2bf(xv.w); l.w = f2bf(xv.w - bf2f(h.w));
    *(ushort4*)(khi + off) = h;
    *(ushort4*)(klo + off) = l;
    ks.x += xv.x; ks.y += xv.y; ks.z += xv.z; ks.w += xv.w;
    float mx = fmaxf(fmaxf(xv.x, xv.y), fmaxf(xv.z, xv.w));
    mx = fmaxf(mx, __shfl_xor(mx, 1));
    mx = fmaxf(mx, __shfl_xor(mx, 2));
    mx = fmaxf(mx, __shfl_xor(mx, 4));
    mx = fmaxf(mx, __shfl_xor(mx, 8));
    mx = fmaxf(mx, __shfl_xor(mx, 16));
    float e0 = __expf(xv.x - mx), e1 = __expf(xv.y - mx);
    float e2 = __expf(xv.z - mx), e3 = __expf(xv.w - mx);
    float es = e0 + e1 + e2 + e3;
    es += __shfl_xor(es, 1);
    es += __shfl_xor(es, 2);
    es += __shfl_xor(es, 4);
    es += __shfl_xor(es, 8);
    es += __shfl_xor(es, 16);
    float inv = 1.f / es;
    Ps4[row * 32 + (c ^ ((row >> 2) & 7))] =
        make_float4(e0 * inv, e1 * inv, e2 * inv, e3 * inv);
  }
  ((float4*)part)[g * 32 + c] = ks;
  __syncthreads();
  if (t < 128) {
    float s = 0.f;
#pragma unroll
    for (int gg = 0; gg < 8; ++gg) s += part[gg * 128 + t];
    kb[(size_t)bid * D + t] = s * (1.f / 64.f);
  }
  __syncthreads();    // Vs + Ps complete
  size_t tb = (size_t)bid * 8192;
#pragma unroll
  for (int pp = 0; pp < 4; ++pp) {
    int d = 32 * pp + (t >> 3);
    int jc = t & 7;
    unsigned hs[8], ls[8], phs[8], pls[8];
#pragma unroll
    for (int i = 0; i < 8; ++i) {
      int j = jc * 8 + i;
      int idx = j * 128 + (d ^ (j & 28));
      float x = Vs[idx];
      unsigned short hh = f2bf(x);
      hs[i] = hh; ls[i] = f2bf(x - bf2f(hh));
      float px = Ps[idx];
      unsigned short phh = f2bf(px);
      phs[i] = phh; pls[i] = f2bf(px - bf2f(phh));
    }
    int4 hw, lw, pw, qw;
    hw.x = (int)(hs[0] | (hs[1] << 16)); hw.y = (int)(hs[2] | (hs[3] << 16));
    hw.z = (int)(hs[4] | (hs[5] << 16)); hw.w = (int)(hs[6] | (hs[7] << 16));
    lw.x = (int)(ls[0] | (ls[1] << 16)); lw.y = (int)(ls[2] | (ls[3] << 16));
    lw.z = (int)(ls[4] | (ls[5] << 16)); lw.w = (int)(ls[6] | (ls[7] << 16));
    pw.x = (int)(phs[0] | (phs[1] << 16)); pw.y = (int)(phs[2] | (phs[3] << 16));
    pw.z = (int)(phs[4] | (phs[5] << 16)); pw.w = (int)(phs[6] | (phs[7] << 16));
    qw.x = (int)(pls[0] | (pls[1] << 16)); qw.y = (int)(pls[2] | (pls[3] << 16));
    qw.z = (int)(pls[4] | (pls[5] << 16)); qw.w = (int)(pls[6] | (pls[7] << 16));
    *(int4*)(vthi  + tb + (size_t)d * 64 + jc * 8) = hw;
    *(int4*)(vtlo  + tb + (size_t)d * 64 + jc * 8) = lw;
    *(int4*)(phith + tb + (size_t)d * 64 + jc * 8) = pw;
    *(int4*)(phitl + tb + (size_t)d * 64 + jc * 8) = qw;
  }
  if (t < 128) {
    float s = 0.f;
#pragma unroll
    for (int row = 0; row < 64; ++row) s += Ps[row * 128 + (t ^ (row & 28))];
    atomicAdd(&ksum[(size_t)(bid >> 5) * D + t], s);
  }
}

// ---------------- K2: 32x32 block scores + top-4 per row ----------------
__global__ __launch_bounds__(256) void k_scores_topk(
    const float* __restrict__ qb, const float* __restrict__ kb, int* __restrict__ lut) {
  __shared__ float qs[NB * D];
  __shared__ float ks[NB * 132];
  __shared__ float sc[NB * 33];
  int bh = blockIdx.x, t = threadIdx.x;
  const float4* qg = (const float4*)(qb + (size_t)bh * NB * D);
  const float4* kg = (const float4*)(kb + (size_t)bh * NB * D);
  float4* qs4 = (float4*)qs;
  float4* ks4 = (float4*)ks;
#pragma unroll
  for (int it = 0; it < 4; ++it) {
    int p = t + 256 * it;
    int row = p >> 5, c = p & 31;
    qs4[p] = qg[p];
    ks4[row * 33 + c] = kg[p];
  }
  __syncthreads();
#pragma unroll
  for (int ss = 0; ss < 4; ++ss) {
    int idx = t + 256 * ss;
    int qr = idx >> 5, kc = idx & 31;
    float acc = 0.f;
#pragma unroll
    for (int c = 0; c < 32; ++c) {
      float4 a = qs4[qr * 32 + c];
      float4 b = ks4[kc * 33 + c];
      acc += a.x * b.x + a.y * b.y + a.z * b.z + a.w * b.w;
    }
    sc[qr * 33 + kc] = acc;
  }
  __syncthreads();
  if (t < NB) {
    unsigned mask = 0;
    for (int s = 0; s < TOPK; ++s) {
      float best = -INFINITY; int bi = 0;
      for (int j = 0; j < NB; ++j) {
        float vv = sc[t * 33 + j];
        if (!((mask >> j) & 1u) && vv > best) { best = vv; bi = j; }
      }
      mask |= 1u << bi;
      lut[((size_t)(bh * NB) + t) * TOPK + s] = bi;
    }
  }
}

// ---------------- K3: MFMA flash sparse attention (XCD-chunked swizzle) -----
__global__ __launch_bounds__(256) void k_attn(
    const float* __restrict__ q,
    const unsigned short* __restrict__ khi, const unsigned short* __restrict__ klo,
    const unsigned short* __restrict__ vthi, const unsigned short* __restrict__ vtlo,
    const int* __restrict__ lut, float* __restrict__ out) {
  extern __shared__ char sm[];
  char* KsH = sm;
  char* KsL = sm + 16384;
  char* VsH = sm + 32768;
  char* VsL = sm + 49152;
  int f = blockIdx.x;
  int n = ((f & 7) << 7) | (f >> 3);
  int qblk = n & 31, bh = n >> 5;
  int t = threadIdx.x, lane = t & 63, w = t >> 6;
  char* PwH = sm + 65536 + w * 4096;
  char* PwL = PwH + 2048;
  int lr = lane & 15, lg = lane >> 4;
  const float scale = 0.088388347648318447f;

  short8 qh[4], ql[4];
  const float* qrow = q + ((size_t)bh * L + (size_t)qblk * 64 + 16 * w + lr) * D;
#pragma unroll
  for (int s = 0; s < 4; ++s) {
    float4 x0 = *(const float4*)(qrow + 32 * s + 8 * lg);
    float4 x1 = *(const float4*)(qrow + 32 * s + 8 * lg + 4);
    float xs[8] = {x0.x, x0.y, x0.z, x0.w, x1.x, x1.y, x1.z, x1.w};
    short8 hv, lv;
#pragma unroll
    for (int i = 0; i < 8; ++i) {
      unsigned short h = f2bf(xs[i]);
      hv[i] = (short)h;
      lv[i] = (short)f2bf(xs[i] - bf2f(h));
    }
    qh[s] = hv; ql[s] = lv;
  }

  f32x4 oacc[8];
#pragma unroll
  for (int i = 0; i < 8; ++i) oacc[i] = (f32x4){0.f, 0.f, 0.f, 0.f};
  float mrun = -INFINITY, lrun = 0.f;

  const int* lp = lut + ((size_t)bh * NB + qblk) * TOPK;
  for (int itb = 0; itb < TOPK; ++itb) {
    int kblk = lp[itb];
    __syncthreads();
    {
      const char* kbh = (const char*)(khi + ((size_t)bh * L + (size_t)kblk * 64) * D);
      const char* kbl = (const char*)(klo + ((size_t)bh * L + (size_t)kblk * 64) * D);
      const char* vbh = (const char*)(vthi + ((size_t)(bh * NB + kblk)) * 8192);
      const char* vbl = (const char*)(vtlo + ((size_t)(bh * NB + kblk)) * 8192);
#pragma unroll
      for (int jj = 0; jj < 4; ++jj) {
        int ib = 4 * w + jj;
        {
          int lrow = 4 * ib + (lane >> 4);
          int soff = lrow * 256 + (((lane & 15) ^ (lrow & 7)) << 4);
          gl_lds16(kbh + soff, KsH + ib * 1024);
          gl_lds16(kbl + soff, KsL + ib * 1024);
        }
        {
          int lrow = 8 * ib + (lane >> 3);
          int soff = lrow * 128 + (((lane & 7) ^ (lrow & 7)) << 4);
          gl_lds16(vbh + soff, VsH + ib * 1024);
          gl_lds16(vbl + soff, VsL + ib * 1024);
        }
      }
    }
    __syncthreads();
    f32x4 sacc[4];
#pragma unroll
    for (int i = 0; i < 4; ++i) sacc[i] = (f32x4){0.f, 0.f, 0.f, 0.f};
#pragma unroll
    for (int s = 0; s < 4; ++s) {
#pragma unroll
      for (int tk = 0; tk < 4; ++tk) {
        int krow = 16 * tk + lr;
        int off = krow * 256 + (((4 * s + lg) ^ (krow & 7)) << 4);
        short8 kH = *(const short8*)(KsH + off);
        short8 kL = *(const short8*)(KsL + off);
        sacc[tk] = mfma16(kH, qh[s], sacc[tk]);
        sacc[tk] = mfma16(kL, qh[s], sacc[tk]);
        sacc[tk] = mfma16(kH, ql[s], sacc[tk]);
      }
    }
    float mloc = -INFINITY;
#pragma unroll
    for (int tk = 0; tk < 4; ++tk)
#pragma unroll
      for (int r = 0; r < 4; ++r) mloc = fmaxf(mloc, sacc[tk][r]);
    mloc = fmaxf(mloc, __shfl_xor(mloc, 16));
    mloc = fmaxf(mloc, __shfl_xor(mloc, 32));
    float mnew = fmaxf(mrun, mloc * scale);
    float alpha = __expf(mrun - mnew);
    float lloc = 0.f;
#pragma unroll
    for (int tk = 0; tk < 4; ++tk) {
      unsigned ph[4], pl[4];
#pragma unroll
      for (int r = 0; r < 4; ++r) {
        float pf = __expf(sacc[tk][r] * scale - mnew);
        lloc += pf;
        unsigned short hh = f2bf(pf);
        ph[r] = hh; pl[r] = f2bf(pf - bf2f(hh));
      }
      int j0b = 32 * tk + 8 * lg;
      int slot16 = j0b >> 4, half = (j0b >> 3) & 1;
      int off = lr * 128 + ((slot16 ^ (lr & 7)) << 4) + half * 8;
      *(int2*)(PwH + off) = make_int2((int)(ph[0] | (ph[1] << 16)),
                                      (int)(ph[2] | (ph[3] << 16)));
      *(int2*)(PwL + off) = make_int2((int)(pl[0] | (pl[1] << 16)),
                                      (int)(pl[2] | (pl[3] << 16)));
    }
    lloc += __shfl_xor(lloc, 16);
    lloc += __shfl_xor(lloc, 32);
    lrun = lrun * alpha + lloc;
    mrun = mnew;
    float ar[4];
#pragma unroll
    for (int r = 0; r < 4; ++r) ar[r] = __shfl(alpha, 4 * lg + r);
#pragma unroll
    for (int tv = 0; tv < 8; ++tv)
#pragma unroll
      for (int r = 0; r < 4; ++r) oacc[tv][r] *= ar[r];
#pragma unroll
    for (int ks = 0; ks < 2; ++ks) {
      int poff = lr * 128 + (((lg + 4 * ks) ^ (lr & 7)) << 4);
      short8 pH = *(const short8*)(PwH + poff);
      short8 pL = *(const short8*)(PwL + poff);
#pragma unroll
      for (int tv = 0; tv < 8; ++tv) {
        int vrow = 16 * tv + lr;
        int voff = vrow * 128 + (((lg + 4 * ks) ^ (vrow & 7)) << 4);
        short8 vH = *(const short8*)(VsH + voff);
        short8 vL = *(const short8*)(VsL + voff);
        oacc[tv] = mfma16(pH, vH, oacc[tv]);
        oacc[tv] = mfma16(pL, vH, oacc[tv]);
        oacc[tv] = mfma16(pH, vL, oacc[tv]);
      }
    }
  }
  float rinv[4];
#pragma unroll
  for (int r = 0; r < 4; ++r) rinv[r] = 1.f / __shfl(lrun, 4 * lg + r);
  float* ob = out + ((size_t)bh * L + (size_t)qblk * 64 + 16 * w) * D;
#pragma unroll
  for (int tv = 0; tv < 8; ++tv)
#pragma unroll
    for (int r = 0; r < 4; ++r)
      ob[(size_t)(4 * lg + r) * D + 16 * tv + lr] = oacc[tv][r] * rinv[r];
}

// ---------------- K4: kvsumT[e][d] partials via MFMA ----------------
__global__ __launch_bounds__(256) void k_kvmm(
    const unsigned short* __restrict__ vthi, const unsigned short* __restrict__ vtlo,
    const unsigned short* __restrict__ phith, const unsigned short* __restrict__ phitl,
    float* __restrict__ part) {
  int slice = blockIdx.x, bh = blockIdx.y;
  int t = threadIdx.x, lane = t & 63, w = t >> 6;
  int lr = lane & 15, lg = lane >> 4;
  f32x4 acc[2][8];
#pragma unroll
  for (int et = 0; et < 2; ++et)
#pragma unroll
    for (int dt = 0; dt < 8; ++dt) acc[et][dt] = (f32x4){0.f, 0.f, 0.f, 0.f};
#pragma unroll
  for (int ks = 0; ks < 4; ++ks) {
    int kblk = 2 * slice + (ks >> 1);
    int li = 32 * (ks & 1);
    size_t base = ((size_t)(bh * NB + kblk)) * 8192 + li + 8 * lg;
    short8 aH[2], aL[2];
#pragma unroll
    for (int et = 0; et < 2; ++et) {
      int e = 32 * w + 16 * et + lr;
      aH[et] = *(const short8*)(vthi + base + (size_t)e * 64);
      aL[et] = *(const short8*)(vtlo + base + (size_t)e * 64);
    }
#pragma unroll
    for (int dt = 0; dt < 8; ++dt) {
      int d = 16 * dt + lr;
      short8 bH = *(const short8*)(phith + base + (size_t)d * 64);
      short8 bL = *(const short8*)(phitl + base + (size_t)d * 64);
#pragma unroll
      for (int et = 0; et < 2; ++et) {
        acc[et][dt] = mfma16(aH[et], bH, acc[et][dt]);
        acc[et][dt] = mfma16(aL[et], bH, acc[et][dt]);
        acc[et][dt] = mfma16(aH[et], bL, acc[et][dt]);
      }
    }
  }
  float* pb = part + ((size_t)(bh * 16 + slice)) * 16384;
#pragma unroll
  for (int et = 0; et < 2; ++et)
#pragma unroll
    for (int dt = 0; dt < 8; ++dt)
#pragma unroll
      for (int r = 0; r < 4; ++r)
        pb[(size_t)(32 * w + 16 * et + 4 * lg + r) * 128 + 16 * dt + lr] =
            acc[et][dt][r];
}

// ---------------- K5: At[j][d] (bf16 hi/lo) = sum_e kvsumT[e][d] * w[j][e] --
__global__ __launch_bounds__(256) void k_projA(
    const float* __restrict__ part, const float* __restrict__ w,
    unsigned short* __restrict__ athi, unsigned short* __restrict__ atlo) {
  extern __shared__ float smA[];
  float* wts   = smA;            // 16384 f, swizzled
  float* kvred = smA + 16384;    // 128 x 32 f
  int dquad = blockIdx.x, bh = blockIdx.y;
  int t = threadIdx.x;
  const float4* wg = (const float4*)w;
#pragma unroll
  for (int it = 0; it < 16; ++it) {
    int p4 = t + 256 * it;
    int j = p4 >> 5, ebase = (p4 & 31) << 2;
    float4 val = wg[p4];
    wts[(ebase + 0) * D + ((j + ebase + 0) & 127)] = val.x;
    wts[(ebase + 1) * D + ((j + ebase + 1) & 127)] = val.y;
    wts[(ebase + 2) * D + ((j + ebase + 2) & 127)] = val.z;
    wts[(ebase + 3) * D + ((j + ebase + 3) & 127)] = val.w;
  }
#pragma unroll
  for (int u = 0; u < 4; ++u) {
    int f4id = t + 256 * u;
    int e = f4id >> 3, dl4 = f4id & 7;
    float4 acc4 = {0.f, 0.f, 0.f, 0.f};
#pragma unroll
    for (int s = 0; s < 16; ++s) {
      float4 p = *(const float4*)(part + ((size_t)(bh * 16 + s)) * 16384 +
                                  (size_t)e * 128 + dquad * 32 + dl4 * 4);
      acc4.x += p.x; acc4.y += p.y; acc4.z += p.z; acc4.w += p.w;
    }
    *(float4*)(kvred + e * 32 + dl4 * 4) = acc4;
  }
  __syncthreads();
  int j = t & 127, dh = t >> 7;
  int dbase = dquad * 32 + dh * 16;
  float acc[16];
#pragma unroll
  for (int u = 0; u < 16; ++u) acc[u] = 0.f;
  for (int e = 0; e < D; ++e) {
    float wv = wts[e * D + ((j + e) & 127)];
#pragma unroll
    for (int dd = 0; dd < 16; ++dd)
      acc[dd] += kvred[e * 32 + dh * 16 + dd] * wv;
  }
  unsigned hs[16], ls[16];
#pragma unroll
  for (int dd = 0; dd < 16; ++dd) {
    unsigned short hh = f2bf(acc[dd]);
    hs[dd] = hh; ls[dd] = f2bf(acc[dd] - bf2f(hh));
  }
  size_t ab = ((size_t)bh * D + j) * D + dbase;
  int4 h0, h1, l0, l1;
  h0.x = (int)(hs[0] | (hs[1] << 16));   h0.y = (int)(hs[2] | (hs[3] << 16));
  h0.z = (int)(hs[4] | (hs[5] << 16));   h0.w = (int)(hs[6] | (hs[7] << 16));
  h1.x = (int)(hs[8] | (hs[9] << 16));   h1.y = (int)(hs[10] | (hs[11] << 16));
  h1.z = (int)(hs[12] | (hs[13] << 16)); h1.w = (int)(hs[14] | (hs[15] << 16));
  l0.x = (int)(ls[0] | (ls[1] << 16));   l0.y = (int)(ls[2] | (ls[3] << 16));
  l0.z = (int)(ls[4] | (ls[5] << 16));   l0.w = (int)(ls[6] | (ls[7] << 16));
  l1.x = (int)(ls[8] | (ls[9] << 16));   l1.y = (int)(ls[10] | (ls[11] << 16));
  l1.z = (int)(ls[12] | (ls[13] << 16)); l1.w = (int)(ls[14] | (ls[15] << 16));
  *(int4*)(athi + ab) = h0;  *(int4*)(athi + ab + 8) = h1;
  *(int4*)(atlo + ab) = l0;  *(int4*)(atlo + ab + 8) = l1;
}

// ---------------- K6: out += (softmax(q) @ At^T)/den + b_proj (MFMA, 0 LDS) -
// Wave w owns q-rows 16w..16w+15 (lane lr = row). A-op = At[j][f] frags,
// B-op = phi frags. acc[dt][r] = num[q=lr][j=16dt+4lg+r].
__global__ __launch_bounds__(256) void k_linout(
    const float* __restrict__ q, const unsigned short* __restrict__ athi,
    const unsigned short* __restrict__ atlo, const float* __restrict__ ksum,
    const float* __restrict__ bproj, float* __restrict__ out) {
  int qblk = blockIdx.x, bh = blockIdx.y;
  int t = threadIdx.x, lane = t & 63, w = t >> 6;
  int lr = lane & 15, lg = lane >> 4;
  const float* qrow = q + ((size_t)bh * L + (size_t)qblk * 64 + 16 * w + lr) * D;
  float xs[4][8];
  float mx = -INFINITY;
#pragma unroll
  for (int s = 0; s < 4; ++s) {
    float4 x0 = *(const float4*)(qrow + 32 * s + 8 * lg);
    float4 x1 = *(const float4*)(qrow + 32 * s + 8 * lg + 4);
    xs[s][0] = x0.x; xs[s][1] = x0.y; xs[s][2] = x0.z; xs[s][3] = x0.w;
    xs[s][4] = x1.x; xs[s][5] = x1.y; xs[s][6] = x1.z; xs[s][7] = x1.w;
#pragma unroll
    for (int i = 0; i < 8; ++i) mx = fmaxf(mx, xs[s][i]);
  }
  mx = fmaxf(mx, __shfl_xor(mx, 16));
  mx = fmaxf(mx, __shfl_xor(mx, 32));
  float es = 0.f;
#pragma unroll
  for (int s = 0; s < 4; ++s)
#pragma unroll
    for (int i = 0; i < 8; ++i) { xs[s][i] = __expf(xs[s][i] - mx); es += xs[s][i]; }
  es += __shfl_xor(es, 16);
  es += __shfl_xor(es, 32);
  float inv = 1.f / es;
  // phi frags + den partial
  const float* kp = ksum + (size_t)bh * D;
  float dpart = 0.f;
  short8 phH[4], phL[4];
#pragma unroll
  for (int s = 0; s < 4; ++s) {
    float4 k0 = *(const float4*)(kp + 32 * s + 8 * lg);
    float4 k1 = *(const float4*)(kp + 32 * s + 8 * lg + 4);
    float kk[8] = {k0.x, k0.y, k0.z, k0.w, k1.x, k1.y, k1.z, k1.w};
    short8 hv, lv;
#pragma unroll
    for (int i = 0; i < 8; ++i) {
      float p = xs[s][i] * inv;
      dpart += p * kk[i];
      unsigned short hh = f2bf(p);
      hv[i] = (short)hh;
      lv[i] = (short)f2bf(p - bf2f(hh));
    }
    phH[s] = hv; phL[s] = lv;
  }
  dpart += __shfl_xor(dpart, 16);
  dpart += __shfl_xor(dpart, 32);
  float rden = 1.f / (1e-5f + dpart);
  f32x4 acc[8];
#pragma unroll
  for (int dt = 0; dt < 8; ++dt) acc[dt] = (f32x4){0.f, 0.f, 0.f, 0.f};
  const unsigned short* ah = athi + (size_t)bh * D * D;
  const unsigned short* al = atlo + (size_t)bh * D * D;
#pragma unroll
  for (int s = 0; s < 4; ++s) {
#pragma unroll
    for (int dt = 0; dt < 8; ++dt) {
      size_t off = (size_t)(16 * dt + lr) * D + 32 * s + 8 * lg;
      short8 aH = *(const short8*)(ah + off);
      short8 aL = *(const short8*)(al + off);
      acc[dt] = mfma16(aH, phH[s], acc[dt]);
      acc[dt] = mfma16(aL, phH[s], acc[dt]);
      acc[dt] = mfma16(aH, phL[s], acc[dt]);
    }
  }
  float* ob = out + ((size_t)bh * L + (size_t)qblk * 64 + 16 * w + lr) * D;
  float4* og4 = (float4*)ob;
  const float4* bg = (const float4*)bproj;
#pragma unroll
  for (int dt = 0; dt < 8; ++dt) {
    int c4 = 4 * dt + lg;
    float4 oo = og4[c4];
    float4 bb = bg[c4];
    oo.x += acc[dt][0] * rden + bb.x;
    oo.y += acc[dt][1] * rden + bb.y;
    oo.z += acc[dt][2] * rden + bb.z;
    oo.w += acc[dt][3] * rden + bb.w;
    og4[c4] = oo;
  }
}

extern "C" void kernel_launch(void* const* d_in, const int* in_sizes, int n_in,
                              void* d_out, int out_size, void* d_ws, size_t ws_size,
                              hipStream_t stream) {
  const float* q = (const float*)d_in[0];
  const float* k = (const float*)d_in[1];
  const float* v = (const float*)d_in[2];
  const float* w = (const float*)d_in[3];
  const float* b = (const float*)d_in[4];
  float* out = (float*)d_out;
  float* ws = (float*)d_ws;
  float* qb    = ws + QB_OFF;
  float* kb    = ws + KB_OFF;
  int*   lut   = (int*)(ws + LUT_OFF);
  float* ksum  = ws + KS_OFF;
  float* partb = ws + PART_OFF;
  unsigned short* athi  = (unsigned short*)(ws + ATHI_OFF);
  unsigned short* atlo  = (unsigned short*)(ws + ATLO_OFF);
  unsigned short* khi   = (unsigned short*)(ws + KHI_OFF);
  unsigned short* klo   = (unsigned short*)(ws + KLO_OFF);
  unsigned short* vthi  = (unsigned short*)(ws + VTHI_OFF);
  unsigned short* vtlo  = (unsigned short*)(ws + VTLO_OFF);
  unsigned short* phith = (unsigned short*)(ws + PHITH_OFF);
  unsigned short* phitl = (unsigned short*)(ws + PHITL_OFF);

  hipFuncSetAttribute(reinterpret_cast<const void*>(k_prep),
                      hipFuncAttributeMaxDynamicSharedMemorySize, 69632);
  hipFuncSetAttribute(reinterpret_cast<const void*>(k_attn),
                      hipFuncAttributeMaxDynamicSharedMemorySize, 81920);
  hipFuncSetAttribute(reinterpret_cast<const void*>(k_projA),
                      hipFuncAttributeMaxDynamicSharedMemorySize, 81920);

  hipMemsetAsync(ksum, 0, 4096 * sizeof(float), stream);

  k_prep       <<<dim3(BH * NB), dim3(256), 69632, stream>>>(
      q, k, v, qb, kb, khi, klo, vthi, vtlo, phith, phitl, ksum);
  k_scores_topk<<<dim3(BH),      dim3(256), 0, stream>>>(qb, kb, lut);
  k_attn       <<<dim3(NB * BH), dim3(256), 81920, stream>>>(
      q, khi, klo, vthi, vtlo, lut, out);
  k_kvmm       <<<dim3(16, BH),  dim3(256), 0, stream>>>(
      vthi, vtlo, phith, phitl, partb);
  k_projA      <<<dim3(4, BH),   dim3(256), 81920, stream>>>(partb, w, athi, atlo);
  k_linout     <<<dim3(NB, BH),  dim3(256), 0, stream>>>(q, athi, atlo, ksum, b, out);
}